// Round 6
// baseline (136.872 us; speedup 1.0000x reference)
//
#include <hip/hip_runtime.h>
#include <hip/hip_bf16.h>
#include <math.h>

#define G 64
#define NNODE 256      // nodes per graph (= O)
#define D_IN 128
#define HDIM 64
#define HEADS 4
#define E_PER 8192
#define NUM_NODES (G * NNODE)
#define E_TOTAL (G * E_PER)
#define BN_EPS 1e-5f

typedef __attribute__((ext_vector_type(8))) short bf16x8;
typedef __attribute__((ext_vector_type(4))) float f32x4;

__device__ __forceinline__ float lrelu02(float x) { return x > 0.f ? x : 0.2f * x; }
__device__ __forceinline__ unsigned short f2bf(float f) {
    unsigned u = __float_as_uint(f);
    return (unsigned short)((u + 0x7FFFu + ((u >> 16) & 1u)) >> 16);
}

// ======================= K0: merged+sorted CSR build =============
// One block per graph. dst-histogram -> scan -> scatter -> per-row
// 64-lane bitonic sort -> ballot duplicate-merge -> (count<<16|src).
__global__ __launch_bounds__(512) void csr_build(
    const int* __restrict__ eidx, unsigned int* __restrict__ mcsr,
    int* __restrict__ rowstart, int* __restrict__ rowlen)
{
    int g = blockIdx.x;
    __shared__ unsigned short ssrcL[E_PER];   // 16 KB
    __shared__ int cnt[NNODE], offv[NNODE + 1], cur[NNODE];
    __shared__ int wsum[8];
    int t = threadIdx.x;
    if (t < NNODE) cnt[t] = 0;
    __syncthreads();

    const int* srcp = eidx + (size_t)g * E_PER;
    const int* dstp = eidx + E_TOTAL + (size_t)g * E_PER;
    int base = g * NNODE;

    for (int e = t; e < E_PER; e += 512) atomicAdd(&cnt[dstp[e] - base], 1);
    __syncthreads();

    int vincl = (t < NNODE) ? cnt[t] : 0;
    #pragma unroll
    for (int d = 1; d < 64; d <<= 1) {
        int o = __shfl_up(vincl, d);
        if ((t & 63) >= d) vincl += o;
    }
    if (t < NNODE && (t & 63) == 63) wsum[t >> 6] = vincl;
    __syncthreads();
    if (t < NNODE) {
        int w = t >> 6;
        int add = 0;
        if (w > 0) add += wsum[0];
        if (w > 1) add += wsum[1];
        if (w > 2) add += wsum[2];
        int ex = vincl - cnt[t] + add;
        offv[t] = ex; cur[t] = ex;
    }
    if (t == 0) offv[NNODE] = E_PER;
    __syncthreads();

    for (int e = t; e < E_PER; e += 512) {
        int s = srcp[e] - base, d = dstp[e] - base;
        int pos = atomicAdd(&cur[d], 1);
        ssrcL[pos] = (unsigned short)s;
    }
    __syncthreads();

    int w = t >> 6, l = t & 63;
    for (int r = w; r < NNODE; r += 8) {
        int rs = offv[r], deg = offv[r + 1] - rs;
        if (deg <= 64) {
            unsigned v = (l < deg) ? (unsigned)ssrcL[rs + l] : 0xFFFFu;
            #pragma unroll
            for (int k = 2; k <= 64; k <<= 1) {
                #pragma unroll
                for (int j = k >> 1; j > 0; j >>= 1) {
                    unsigned pv = (unsigned)__shfl_xor((int)v, j);
                    bool up = ((l & k) == 0);
                    bool lower = ((l & j) == 0);
                    unsigned mn = v < pv ? v : pv;
                    unsigned mx = v < pv ? pv : v;
                    v = (up == lower) ? mn : mx;
                }
            }
            unsigned prev = (unsigned)__shfl_up((int)v, 1);
            bool lead = (l < deg) && (l == 0 || v != prev);
            unsigned long long L = __ballot(lead);
            if (lead) {
                unsigned long long gt = (l >= 63) ? 0ULL : (L & (~0ULL << (l + 1)));
                int nxt = gt ? __builtin_ctzll(gt) : deg;
                int count = nxt - l;
                unsigned long long below = (l == 0) ? 0ULL : (L & ((1ULL << l) - 1ULL));
                int rank = __builtin_popcountll(below);
                mcsr[(size_t)g * E_PER + rs + rank] =
                    ((unsigned)count << 16) | (v & 0xFFFFu);
            }
            if (l == 0) {
                rowlen[g * NNODE + r] = __builtin_popcountll(L);
                rowstart[g * NNODE + r] = rs;
            }
        } else if (l == 0) {
            // rare slow path: serial insertion sort + merge
            for (int i = 1; i < deg; ++i) {
                unsigned short key = ssrcL[rs + i];
                int j = i - 1;
                while (j >= 0 && ssrcL[rs + j] > key) { ssrcL[rs + j + 1] = ssrcL[rs + j]; --j; }
                ssrcL[rs + j + 1] = key;
            }
            int m = 0, i = 0;
            while (i < deg) {
                int s0 = ssrcL[rs + i]; int c = 1;
                while (i + c < deg && ssrcL[rs + i + c] == s0) ++c;
                mcsr[(size_t)g * E_PER + rs + m] = ((unsigned)c << 16) | (unsigned)s0;
                ++m; i += c;
            }
            rowlen[g * NNODE + r] = m;
            rowstart[g * NNODE + r] = rs;
        }
    }
}

// ======================= K1: omics encoder =======================
__global__ __launch_bounds__(256) void enc_kernel(
    const float* __restrict__ omics, const float* __restrict__ w,
    const float* __restrict__ b, const float* __restrict__ rot,
    const float* __restrict__ gamma, const float* __restrict__ beta,
    const float* __restrict__ mean, const float* __restrict__ var,
    float* __restrict__ x)
{
    int o = blockIdx.x;
    __shared__ float Wl[D_IN * HDIM];       // 32 KB
    __shared__ float Om[G * 132];           // 33 KB
    int t = threadIdx.x;
    for (int i = t; i < D_IN * HDIM / 4; i += 256)
        ((float4*)Wl)[i] = ((const float4*)(w + (size_t)o * D_IN * HDIM))[i];
    for (int i = t; i < G * (D_IN / 4); i += 256) {
        int g = i >> 5, dq = i & 31;
        *((float4*)(Om + g * 132) + dq) =
            ((const float4*)(omics + ((size_t)g * NNODE + o) * D_IN))[dq];
    }
    __syncthreads();

    int w4 = t >> 6, l = t & 63;
    int cq = l & 15, gsub = l >> 4;
    int gbase = w4 * 4 + gsub;
    float4 acc[4];
    #pragma unroll
    for (int gi = 0; gi < 4; ++gi) acc[gi] = make_float4(0.f, 0.f, 0.f, 0.f);

    for (int d = 0; d < D_IN; ++d) {
        float4 wv = *(const float4*)&Wl[d * 64 + cq * 4];
        #pragma unroll
        for (int gi = 0; gi < 4; ++gi) {
            float ov = Om[(gi * 16 + gbase) * 132 + d];
            acc[gi].x = fmaf(ov, wv.x, acc[gi].x);
            acc[gi].y = fmaf(ov, wv.y, acc[gi].y);
            acc[gi].z = fmaf(ov, wv.z, acc[gi].z);
            acc[gi].w = fmaf(ov, wv.w, acc[gi].w);
        }
    }

    float4 bv = ((const float4*)b)[o * 16 + cq];
    float4 rv = ((const float4*)rot)[o * 16 + cq];
    float4 mv = ((const float4*)mean)[o * 16 + cq];
    float4 vv = ((const float4*)var)[o * 16 + cq];
    float4 gv = ((const float4*)gamma)[o * 16 + cq];
    float4 be = ((const float4*)beta)[o * 16 + cq];
    float4 sc, kk;
    sc.x = cosf(rv.x) + sinf(rv.x); sc.y = cosf(rv.y) + sinf(rv.y);
    sc.z = cosf(rv.z) + sinf(rv.z); sc.w = cosf(rv.w) + sinf(rv.w);
    kk.x = gv.x * rsqrtf(vv.x + BN_EPS); kk.y = gv.y * rsqrtf(vv.y + BN_EPS);
    kk.z = gv.z * rsqrtf(vv.z + BN_EPS); kk.w = gv.w * rsqrtf(vv.w + BN_EPS);

    #pragma unroll
    for (int gi = 0; gi < 4; ++gi) {
        int g = gi * 16 + gbase;
        float4 v;
        v.x = fmaxf((acc[gi].x + bv.x) * sc.x, 0.f);
        v.y = fmaxf((acc[gi].y + bv.y) * sc.y, 0.f);
        v.z = fmaxf((acc[gi].z + bv.z) * sc.z, 0.f);
        v.w = fmaxf((acc[gi].w + bv.w) * sc.w, 0.f);
        v.x = (v.x - mv.x) * kk.x + be.x;
        v.y = (v.y - mv.y) * kk.y + be.y;
        v.z = (v.z - mv.z) * kk.z + be.z;
        v.w = (v.w - mv.w) * kk.w + be.w;
        *(float4*)&x[((size_t)(g * NNODE + o)) * 64 + cq * 4] = v;
    }
}

// ======================= K2: GAT1 linear =========================
__global__ __launch_bounds__(256) void gat1_lin(
    const float* __restrict__ x, const float* __restrict__ W,
    const float* __restrict__ att_s, const float* __restrict__ att_d,
    float* __restrict__ h1, float* __restrict__ as1, float* __restrict__ ad1)
{
    int blk = blockIdx.x;
    __shared__ float Xl[64 * 65];
    __shared__ float Wl[64 * 256];
    int t = threadIdx.x;
    int node0 = blk * 64;
    for (int i = t; i < 64 * 64; i += 256) {
        int nl = i >> 6, k = i & 63;
        Xl[nl * 65 + k] = x[(size_t)node0 * HDIM + i];
    }
    for (int i = t; i < 64 * 256 / 4; i += 256)
        ((float4*)Wl)[i] = ((const float4*)W)[i];
    __syncthreads();

    int w = t >> 6, l = t & 63;
    int nsub = l >> 2, csel = l & 3;
    float4 acc[4][4];
    #pragma unroll
    for (int ni = 0; ni < 4; ++ni)
        #pragma unroll
        for (int cj = 0; cj < 4; ++cj) acc[ni][cj] = make_float4(0.f, 0.f, 0.f, 0.f);

    for (int k = 0; k < 64; ++k) {
        float4 wv[4];
        #pragma unroll
        for (int cj = 0; cj < 4; ++cj)
            wv[cj] = *(const float4*)&Wl[k * 256 + w * 64 + cj * 16 + csel * 4];
        #pragma unroll
        for (int ni = 0; ni < 4; ++ni) {
            float xv = Xl[(ni * 16 + nsub) * 65 + k];
            #pragma unroll
            for (int cj = 0; cj < 4; ++cj) {
                acc[ni][cj].x = fmaf(xv, wv[cj].x, acc[ni][cj].x);
                acc[ni][cj].y = fmaf(xv, wv[cj].y, acc[ni][cj].y);
                acc[ni][cj].z = fmaf(xv, wv[cj].z, acc[ni][cj].z);
                acc[ni][cj].w = fmaf(xv, wv[cj].w, acc[ni][cj].w);
            }
        }
    }

    float4 as_w[4], ad_w[4];
    #pragma unroll
    for (int cj = 0; cj < 4; ++cj) {
        as_w[cj] = ((const float4*)att_s)[w * 16 + cj * 4 + csel];
        ad_w[cj] = ((const float4*)att_d)[w * 16 + cj * 4 + csel];
    }
    #pragma unroll
    for (int ni = 0; ni < 4; ++ni) {
        int n = ni * 16 + nsub;
        float asv = 0.f, adv = 0.f;
        #pragma unroll
        for (int cj = 0; cj < 4; ++cj) {
            asv += acc[ni][cj].x * as_w[cj].x + acc[ni][cj].y * as_w[cj].y
                 + acc[ni][cj].z * as_w[cj].z + acc[ni][cj].w * as_w[cj].w;
            adv += acc[ni][cj].x * ad_w[cj].x + acc[ni][cj].y * ad_w[cj].y
                 + acc[ni][cj].z * ad_w[cj].z + acc[ni][cj].w * ad_w[cj].w;
            *(float4*)&h1[((size_t)(node0 + n) * HEADS + w) * 64 + cj * 16 + csel * 4]
                = acc[ni][cj];
        }
        asv += __shfl_xor(asv, 1); asv += __shfl_xor(asv, 2);
        adv += __shfl_xor(adv, 1); adv += __shfl_xor(adv, 2);
        if (csel == 0) {
            as1[(node0 + n) * HEADS + w] = asv;
            ad1[(node0 + n) * HEADS + w] = adv;
        }
    }
}

// ======================= K3: GAT1 edge via merged-CSR MFMA =======
// grid (G, HEADS, 2), 512 thr, 2 blocks/CU. Each block: 2 dst-quarters,
// Mb filled bf16 directly (no atomics/cvt), full K=256 MFMA per quarter.
__global__ __launch_bounds__(512) void gat1_edge_mfma(
    const float* __restrict__ h1, const float* __restrict__ as1,
    const float* __restrict__ ad1, const unsigned int* __restrict__ mcsr,
    const int* __restrict__ rowstart, const int* __restrict__ rowlen,
    const float* __restrict__ bias1, float* __restrict__ x2)
{
    int g = blockIdx.x, head = blockIdx.y, by = blockIdx.z;
    __shared__ unsigned short ht[64 * NNODE];   // 32 KB bf16 H^T, oct^(c&31)
    __shared__ unsigned short Mb[64 * NNODE];   // 32 KB bf16 M, oct^(row&7)
    __shared__ float asl[NNODE], adl[NNODE], u1[NNODE], u2[NNODE];
    __shared__ float v1[NNODE], v2[NNODE], den[64];
    __shared__ float wred[8];
    int t = threadIdx.x;

    float va = -1e30f, vd = 0.f;
    if (t < NNODE) {
        va = as1[(g * NNODE + t) * HEADS + head];
        vd = ad1[(g * NNODE + t) * HEADS + head];
        asl[t] = va; adl[t] = vd;
    }
    {
        float mv = va;
        #pragma unroll
        for (int d = 32; d; d >>= 1) mv = fmaxf(mv, __shfl_xor(mv, d));
        if ((t & 63) == 0) wred[t >> 6] = mv;
    }
    __syncthreads();
    if (t < NNODE) {
        float M = fmaxf(fmaxf(wred[0], wred[1]), fmaxf(wred[2], wred[3]));
        float mt = lrelu02(M + vd);
        v1[t] = __expf(vd - mt);
        v2[t] = __expf(0.2f * vd - mt);
        u1[t] = __expf(va);
        u2[t] = __expf(0.2f * va);
    }
    for (int i = t; i < NNODE * 16; i += 512) {
        int s = i >> 4, cq = i & 15;
        float4 hv = ((const float4*)h1)[((size_t)(g * NNODE + s) * HEADS + head) * 16 + cq];
        int c0 = cq * 4;
        ht[(c0 + 0) * 256 + (((s >> 3) ^ ((c0 + 0) & 31)) << 3) + (s & 7)] = f2bf(hv.x);
        ht[(c0 + 1) * 256 + (((s >> 3) ^ ((c0 + 1) & 31)) << 3) + (s & 7)] = f2bf(hv.y);
        ht[(c0 + 2) * 256 + (((s >> 3) ^ ((c0 + 2) & 31)) << 3) + (s & 7)] = f2bf(hv.z);
        ht[(c0 + 3) * 256 + (((s >> 3) ^ ((c0 + 3) & 31)) << 3) + (s & 7)] = f2bf(hv.w);
    }
    __syncthreads();

    int w = t >> 6, l = t & 63;
    int lrow = l & 15, lk = l >> 4;

    for (int qi = 0; qi < 2; ++qi) {
        int q = by * 2 + qi;
        int r0 = q * 64;
        // zero Mb (32 KB)
        float4 z4 = make_float4(0.f, 0.f, 0.f, 0.f);
        for (int i = t; i < 2048; i += 512) ((float4*)Mb)[i] = z4;
        __syncthreads();
        // fill: wave per dst row, bf16 plain stores, den via shfl reduce
        for (int ri = w; ri < 64; ri += 8) {
            int d = r0 + ri;
            int rs = rowstart[g * NNODE + d], len = rowlen[g * NNODE + d];
            float adv = adl[d], vd1 = v1[d], vd2 = v2[d];
            float ss = 0.f;
            for (int e0 = 0; e0 < len; e0 += 64) {
                int e = e0 + l;
                float p = 0.f;
                if (e < len) {
                    unsigned ent = mcsr[(size_t)g * E_PER + rs + e];
                    int s = ent & 0xFFFFu;
                    float c = (float)(ent >> 16);
                    float z = asl[s] + adv;
                    p = c * (z > 0.f ? u1[s] * vd1 : u2[s] * vd2);
                    Mb[ri * 256 + ((((s >> 3) ^ (ri & 7)) << 3) | (s & 7))] = f2bf(p);
                }
                ss += p;
            }
            #pragma unroll
            for (int m = 1; m < 64; m <<= 1) ss += __shfl_xor(ss, m);
            if (l == 0) den[ri] = ss;
        }
        __syncthreads();
        // MFMA: wave w -> m-tile (w&3), n-tiles {(w>>2)*2, +1}; K=256
        int mt = w & 3, nb = (w >> 2) * 2;
        f32x4 acc0 = {0.f, 0.f, 0.f, 0.f};
        f32x4 acc1 = {0.f, 0.f, 0.f, 0.f};
        int ar = mt * 16 + lrow;
        int c0 = nb * 16 + lrow, c1 = c0 + 16;
        #pragma unroll
        for (int kb = 0; kb < 8; ++kb) {
            int oct = kb * 4 + lk;
            bf16x8 a = *(const bf16x8*)&Mb[ar * 256 + ((oct ^ (ar & 7)) << 3)];
            bf16x8 b0 = *(const bf16x8*)&ht[c0 * 256 + ((oct ^ (c0 & 31)) << 3)];
            bf16x8 b1 = *(const bf16x8*)&ht[c1 * 256 + ((oct ^ (c1 & 31)) << 3)];
            acc0 = __builtin_amdgcn_mfma_f32_16x16x32_bf16(a, b0, acc0, 0, 0, 0);
            acc1 = __builtin_amdgcn_mfma_f32_16x16x32_bf16(a, b1, acc1, 0, 0, 0);
        }
        // epilogue
        #pragma unroll
        for (int r = 0; r < 4; ++r) {
            int rl = mt * 16 + lk * 4 + r;
            int d = r0 + rl;
            float inv = 1.f / (den[rl] + 1e-16f);
            float o0 = acc0[r] * inv + bias1[head * 64 + c0 - lrow + lrow];  // col c0
            float o1 = acc1[r] * inv + bias1[head * 64 + c1];
            o0 = acc0[r] * inv + bias1[head * 64 + c0];
            o0 = o0 > 0.f ? o0 : expm1f(o0);
            o1 = o1 > 0.f ? o1 : expm1f(o1);
            size_t ob = (size_t)(g * NNODE + d) * 256 + head * 64;
            x2[ob + c0] = o0;
            x2[ob + c1] = o1;
        }
        __syncthreads();
    }
}

// ======================= K4: GAT2 linear =========================
__global__ __launch_bounds__(256) void gat2_lin(
    const float* __restrict__ x2, const float* __restrict__ W,
    const float* __restrict__ att_s, const float* __restrict__ att_d,
    float* __restrict__ h2, float* __restrict__ as2, float* __restrict__ ad2)
{
    int blk = blockIdx.x;
    __shared__ float Xl[64 * 260];
    __shared__ float Wl[256 * 64];
    int t = threadIdx.x;
    int node0 = blk * 64;
    for (int i = t; i < 64 * 64; i += 256) {
        int nl = i >> 6, kq = i & 63;
        *((float4*)(Xl + nl * 260) + kq) =
            ((const float4*)(x2 + (size_t)(node0 + nl) * 256))[kq];
    }
    for (int i = t; i < 256 * 64 / 4; i += 256)
        ((float4*)Wl)[i] = ((const float4*)W)[i];
    __syncthreads();

    int w = t >> 6, l = t & 63;
    int cq = l & 15, nsub = l >> 4;
    float4 acc[4];
    #pragma unroll
    for (int ni = 0; ni < 4; ++ni) acc[ni] = make_float4(0.f, 0.f, 0.f, 0.f);

    for (int k0 = 0; k0 < 256; k0 += 4) {
        float4 wv[4];
        #pragma unroll
        for (int kk = 0; kk < 4; ++kk)
            wv[kk] = *(const float4*)&Wl[(k0 + kk) * 64 + cq * 4];
        #pragma unroll
        for (int ni = 0; ni < 4; ++ni) {
            float4 xq = *(const float4*)&Xl[(w * 16 + ni * 4 + nsub) * 260 + k0];
            acc[ni].x = fmaf(xq.x, wv[0].x, acc[ni].x);
            acc[ni].y = fmaf(xq.x, wv[0].y, acc[ni].y);
            acc[ni].z = fmaf(xq.x, wv[0].z, acc[ni].z);
            acc[ni].w = fmaf(xq.x, wv[0].w, acc[ni].w);
            acc[ni].x = fmaf(xq.y, wv[1].x, acc[ni].x);
            acc[ni].y = fmaf(xq.y, wv[1].y, acc[ni].y);
            acc[ni].z = fmaf(xq.y, wv[1].z, acc[ni].z);
            acc[ni].w = fmaf(xq.y, wv[1].w, acc[ni].w);
            acc[ni].x = fmaf(xq.z, wv[2].x, acc[ni].x);
            acc[ni].y = fmaf(xq.z, wv[2].y, acc[ni].y);
            acc[ni].z = fmaf(xq.z, wv[2].z, acc[ni].z);
            acc[ni].w = fmaf(xq.z, wv[2].w, acc[ni].w);
            acc[ni].x = fmaf(xq.w, wv[3].x, acc[ni].x);
            acc[ni].y = fmaf(xq.w, wv[3].y, acc[ni].y);
            acc[ni].z = fmaf(xq.w, wv[3].z, acc[ni].z);
            acc[ni].w = fmaf(xq.w, wv[3].w, acc[ni].w);
        }
    }

    float4 as_w = ((const float4*)att_s)[cq];
    float4 ad_w = ((const float4*)att_d)[cq];
    #pragma unroll
    for (int ni = 0; ni < 4; ++ni) {
        int n = w * 16 + ni * 4 + nsub;
        float asv = acc[ni].x * as_w.x + acc[ni].y * as_w.y
                  + acc[ni].z * as_w.z + acc[ni].w * as_w.w;
        float adv = acc[ni].x * ad_w.x + acc[ni].y * ad_w.y
                  + acc[ni].z * ad_w.z + acc[ni].w * ad_w.w;
        #pragma unroll
        for (int m = 1; m <= 8; m <<= 1) {
            asv += __shfl_xor(asv, m);
            adv += __shfl_xor(adv, m);
        }
        *(float4*)&h2[(size_t)(node0 + n) * 64 + cq * 4] = acc[ni];
        if (cq == 0) { as2[node0 + n] = asv; ad2[node0 + n] = adv; }
    }
}

// ======================= K5: GAT2 edge MFMA + partial pool =======
// grid (G, 8): each block = 32 dst rows; output only the pooled partial.
__global__ __launch_bounds__(512) void gat2_edge_mfma(
    const float* __restrict__ h2, const float* __restrict__ as2,
    const float* __restrict__ ad2, const unsigned int* __restrict__ mcsr,
    const int* __restrict__ rowstart, const int* __restrict__ rowlen,
    float* __restrict__ pl8)
{
    int g = blockIdx.x, by = blockIdx.y;
    __shared__ unsigned short ht[64 * NNODE];   // 32 KB
    __shared__ unsigned short Mb[32 * NNODE];   // 16 KB
    __shared__ float asl[NNODE], adl[NNODE], u1[NNODE], u2[NNODE];
    __shared__ float v1[NNODE], v2[NNODE], den[32];
    __shared__ float wred[8];
    __shared__ float pool[64];
    int t = threadIdx.x;

    float va = -1e30f, vd = 0.f;
    if (t < NNODE) {
        va = as2[g * NNODE + t];
        vd = ad2[g * NNODE + t];
        asl[t] = va; adl[t] = vd;
    }
    if (t < 64) pool[t] = 0.f;
    {
        float mv = va;
        #pragma unroll
        for (int d = 32; d; d >>= 1) mv = fmaxf(mv, __shfl_xor(mv, d));
        if ((t & 63) == 0) wred[t >> 6] = mv;
    }
    __syncthreads();
    if (t < NNODE) {
        float M = fmaxf(fmaxf(wred[0], wred[1]), fmaxf(wred[2], wred[3]));
        float mt = lrelu02(M + vd);
        v1[t] = __expf(vd - mt);
        v2[t] = __expf(0.2f * vd - mt);
        u1[t] = __expf(va);
        u2[t] = __expf(0.2f * va);
    }
    for (int i = t; i < NNODE * 16; i += 512) {
        int s = i >> 4, cq = i & 15;
        float4 hv = ((const float4*)h2)[(size_t)g * NNODE * 16 + i];
        int c0 = cq * 4;
        ht[(c0 + 0) * 256 + (((s >> 3) ^ ((c0 + 0) & 31)) << 3) + (s & 7)] = f2bf(hv.x);
        ht[(c0 + 1) * 256 + (((s >> 3) ^ ((c0 + 1) & 31)) << 3) + (s & 7)] = f2bf(hv.y);
        ht[(c0 + 2) * 256 + (((s >> 3) ^ ((c0 + 2) & 31)) << 3) + (s & 7)] = f2bf(hv.z);
        ht[(c0 + 3) * 256 + (((s >> 3) ^ ((c0 + 3) & 31)) << 3) + (s & 7)] = f2bf(hv.w);
    }
    float4 z4 = make_float4(0.f, 0.f, 0.f, 0.f);
    for (int i = t; i < 1024; i += 512) ((float4*)Mb)[i] = z4;
    __syncthreads();

    int w = t >> 6, l = t & 63;
    int lrow = l & 15, lk = l >> 4;
    int r0 = by * 32;

    for (int ri = w; ri < 32; ri += 8) {
        int d = r0 + ri;
        int rs = rowstart[g * NNODE + d], len = rowlen[g * NNODE + d];
        float adv = adl[d], vd1 = v1[d], vd2 = v2[d];
        float ss = 0.f;
        for (int e0 = 0; e0 < len; e0 += 64) {
            int e = e0 + l;
            float p = 0.f;
            if (e < len) {
                unsigned ent = mcsr[(size_t)g * E_PER + rs + e];
                int s = ent & 0xFFFFu;
                float c = (float)(ent >> 16);
                float z = asl[s] + adv;
                p = c * (z > 0.f ? u1[s] * vd1 : u2[s] * vd2);
                Mb[ri * 256 + ((((s >> 3) ^ (ri & 7)) << 3) | (s & 7))] = f2bf(p);
            }
            ss += p;
        }
        #pragma unroll
        for (int m = 1; m < 64; m <<= 1) ss += __shfl_xor(ss, m);
        if (l == 0) den[ri] = ss;
    }
    __syncthreads();

    int mt = w & 1, nt = w >> 1;
    f32x4 acc = {0.f, 0.f, 0.f, 0.f};
    int ar = mt * 16 + lrow;
    int c = nt * 16 + lrow;
    #pragma unroll
    for (int kb = 0; kb < 8; ++kb) {
        int oct = kb * 4 + lk;
        bf16x8 a = *(const bf16x8*)&Mb[ar * 256 + ((oct ^ (ar & 7)) << 3)];
        bf16x8 b = *(const bf16x8*)&ht[c * 256 + ((oct ^ (c & 31)) << 3)];
        acc = __builtin_amdgcn_mfma_f32_16x16x32_bf16(a, b, acc, 0, 0, 0);
    }
    // pool partial: sum over this block's 32 rows of acc/den
    float ps = 0.f;
    #pragma unroll
    for (int r = 0; r < 4; ++r) {
        int rl = mt * 16 + lk * 4 + r;
        ps = fmaf(acc[r], 1.f / (den[rl] + 1e-16f), ps);
    }
    ps += __shfl_xor(ps, 16);
    ps += __shfl_xor(ps, 32);
    if (l < 16) atomicAdd(&pool[nt * 16 + lrow], ps);
    __syncthreads();
    if (t < 64) pl8[(size_t)(g * 8 + by) * 64 + t] = pool[t];
}

// ======================= K6: pool-combine + classifier ===========
__global__ __launch_bounds__(64) void cls_kernel(
    const float* __restrict__ pl8, const float* __restrict__ bias2,
    const float* __restrict__ w1, const float* __restrict__ b1,
    const float* __restrict__ w2, const float* __restrict__ b2,
    float* __restrict__ outv, float* __restrict__ pooled)
{
    int g = blockIdx.x, c = threadIdx.x;
    float po = 0.f;
    #pragma unroll
    for (int q = 0; q < 8; ++q) po += pl8[(size_t)(g * 8 + q) * 64 + c];
    po = po * (1.f / 256.f) + bias2[c];
    pooled[g * 64 + c] = po;
    __shared__ float poL[64];
    poL[c] = po;
    __syncthreads();
    float acc = b1[c];
    for (int k = 0; k < 64; ++k) acc = fmaf(poL[k], w1[k * 64 + c], acc);
    acc = fmaxf(acc, 0.f);
    float contrib = acc * w2[c];
    #pragma unroll
    for (int d = 32; d; d >>= 1) contrib += __shfl_xor(contrib, d);
    if (c == 0) outv[g] = 1.f / (1.f + __expf(-contrib));
}

extern "C" void kernel_launch(void* const* d_in, const int* in_sizes, int n_in,
                              void* d_out, int out_size, void* d_ws, size_t ws_size,
                              hipStream_t stream) {
    const float* omics   = (const float*)d_in[0];
    const float* w_omics = (const float*)d_in[1];
    const float* b_omics = (const float*)d_in[2];
    const float* rot     = (const float*)d_in[3];
    const float* bn_g    = (const float*)d_in[4];
    const float* bn_b    = (const float*)d_in[5];
    const float* bn_m    = (const float*)d_in[6];
    const float* bn_v    = (const float*)d_in[7];
    const float* gat1_w  = (const float*)d_in[8];
    const float* att_s1  = (const float*)d_in[9];
    const float* att_d1  = (const float*)d_in[10];
    const float* bias1   = (const float*)d_in[11];
    const float* gat2_w  = (const float*)d_in[12];
    const float* att_s2  = (const float*)d_in[13];
    const float* att_d2  = (const float*)d_in[14];
    const float* bias2   = (const float*)d_in[15];
    const float* cls_w1  = (const float*)d_in[16];
    const float* cls_b1  = (const float*)d_in[17];
    const float* cls_w2  = (const float*)d_in[18];
    const float* cls_b2  = (const float*)d_in[19];
    const int*   eidx    = (const int*)d_in[20];

    float* ws = (float*)d_ws;
    size_t o_x    = 0;
    size_t o_h1   = o_x  + (size_t)NUM_NODES * HDIM;
    size_t o_as1  = o_h1 + (size_t)NUM_NODES * HEADS * 64;
    size_t o_ad1  = o_as1 + (size_t)NUM_NODES * HEADS;
    size_t o_x2   = o_ad1 + (size_t)NUM_NODES * HEADS;
    size_t o_h2   = o_x2 + (size_t)NUM_NODES * HEADS * 64;
    size_t o_as2  = o_h2 + (size_t)NUM_NODES * 64;
    size_t o_ad2  = o_as2 + (size_t)NUM_NODES;
    size_t o_pl8  = o_ad2 + (size_t)NUM_NODES;
    size_t o_mcsr = o_pl8 + (size_t)G * 8 * 64;
    size_t o_rs   = o_mcsr + (size_t)E_TOTAL;        // mcsr u32, 1 f32 unit each
    size_t o_rl   = o_rs + (size_t)NUM_NODES;

    float* x   = ws + o_x;
    float* h1  = ws + o_h1;
    float* as1 = ws + o_as1;
    float* ad1 = ws + o_ad1;
    float* x2  = ws + o_x2;
    float* h2  = ws + o_h2;
    float* as2 = ws + o_as2;
    float* ad2 = ws + o_ad2;
    float* pl8 = ws + o_pl8;
    unsigned int* mcsr = (unsigned int*)(ws + o_mcsr);
    int* rowstart_ws = (int*)(ws + o_rs);
    int* rowlen_ws   = (int*)(ws + o_rl);

    float* outv   = (float*)d_out;        // [64]
    float* pooled = (float*)d_out + G;    // [64*64]

    csr_build<<<G, 512, 0, stream>>>(eidx, mcsr, rowstart_ws, rowlen_ws);
    enc_kernel<<<256, 256, 0, stream>>>(omics, w_omics, b_omics, rot,
                                        bn_g, bn_b, bn_m, bn_v, x);
    gat1_lin<<<256, 256, 0, stream>>>(x, gat1_w, att_s1, att_d1, h1, as1, ad1);
    gat1_edge_mfma<<<dim3(G, HEADS, 2), 512, 0, stream>>>(
        h1, as1, ad1, mcsr, rowstart_ws, rowlen_ws, bias1, x2);
    gat2_lin<<<256, 256, 0, stream>>>(x2, gat2_w, att_s2, att_d2, h2, as2, ad2);
    gat2_edge_mfma<<<dim3(G, 8), 512, 0, stream>>>(
        h2, as2, ad2, mcsr, rowstart_ws, rowlen_ws, pl8);
    cls_kernel<<<G, 64, 0, stream>>>(pl8, bias2, cls_w1, cls_b1, cls_w2, cls_b2,
                                     outv, pooled);
}

// Round 7
// 111.425 us; speedup vs baseline: 1.2284x; 1.2284x over previous
//
#include <hip/hip_runtime.h>
#include <hip/hip_bf16.h>
#include <math.h>

#define G 64
#define NNODE 256      // nodes per graph (= O)
#define D_IN 128
#define HDIM 64
#define HEADS 4
#define E_PER 8192
#define NUM_NODES (G * NNODE)
#define E_TOTAL (G * E_PER)
#define BN_EPS 1e-5f

#define CSR_SPLIT 8
#define CSR_ROWS (NNODE / CSR_SPLIT)    // 32 rows per block
#define CSR_BUF 2176                    // >> E[slice]=1024, Binomial tail safe

typedef __attribute__((ext_vector_type(8))) short bf16x8;
typedef __attribute__((ext_vector_type(4))) float f32x4;

__device__ __forceinline__ float lrelu02(float x) { return x > 0.f ? x : 0.2f * x; }
__device__ __forceinline__ unsigned short f2bf(float f) {
    unsigned u = __float_as_uint(f);
    return (unsigned short)((u + 0x7FFFu + ((u >> 16) & 1u)) >> 16);
}

// ======================= K0: merged+sorted CSR build =============
// grid (G, 8): each block redundantly histograms+scans the graph's dst
// list (cheap), scatters only its 32-row slice, sorts 4 rows/wave.
__global__ __launch_bounds__(512) void csr_build(
    const int* __restrict__ eidx, unsigned int* __restrict__ mcsr,
    int* __restrict__ rowstart, int* __restrict__ rowlen)
{
    int g = blockIdx.x, by = blockIdx.y;
    __shared__ unsigned short ssrcL[CSR_BUF];   // ~4.3 KB
    __shared__ int cnt[NNODE], offv[NNODE + 1];
    __shared__ int cur[CSR_ROWS];
    __shared__ int wsum[8];
    int t = threadIdx.x;
    if (t < NNODE) cnt[t] = 0;
    __syncthreads();

    const int* srcp = eidx + (size_t)g * E_PER;
    const int* dstp = eidx + E_TOTAL + (size_t)g * E_PER;
    int base = g * NNODE;

    for (int e = t; e < E_PER; e += 512) atomicAdd(&cnt[dstp[e] - base], 1);
    __syncthreads();

    int vincl = (t < NNODE) ? cnt[t] : 0;
    #pragma unroll
    for (int d = 1; d < 64; d <<= 1) {
        int o = __shfl_up(vincl, d);
        if ((t & 63) >= d) vincl += o;
    }
    if (t < NNODE && (t & 63) == 63) wsum[t >> 6] = vincl;
    __syncthreads();
    if (t < NNODE) {
        int w = t >> 6;
        int add = 0;
        if (w > 0) add += wsum[0];
        if (w > 1) add += wsum[1];
        if (w > 2) add += wsum[2];
        offv[t] = vincl - cnt[t] + add;
    }
    if (t == 0) offv[NNODE] = E_PER;
    __syncthreads();

    int r0 = by * CSR_ROWS;
    int lb = offv[r0];
    if (t < CSR_ROWS) cur[t] = offv[r0 + t] - lb;
    __syncthreads();

    // scatter only this block's row slice (local positions)
    for (int e = t; e < E_PER; e += 512) {
        int d = dstp[e] - base - r0;
        if ((unsigned)d < CSR_ROWS) {
            int s = srcp[e] - base;
            int pos = atomicAdd(&cur[d], 1);
            ssrcL[pos] = (unsigned short)s;
        }
    }
    __syncthreads();

    int w = t >> 6, l = t & 63;
    for (int ri = w; ri < CSR_ROWS; ri += 8) {
        int r = r0 + ri;
        int rsg = offv[r], deg = offv[r + 1] - rsg;
        int ls = rsg - lb;
        if (deg <= 64) {
            unsigned v = (l < deg) ? (unsigned)ssrcL[ls + l] : 0xFFFFu;
            #pragma unroll
            for (int k = 2; k <= 64; k <<= 1) {
                #pragma unroll
                for (int j = k >> 1; j > 0; j >>= 1) {
                    unsigned pv = (unsigned)__shfl_xor((int)v, j);
                    bool up = ((l & k) == 0);
                    bool lower = ((l & j) == 0);
                    unsigned mn = v < pv ? v : pv;
                    unsigned mx = v < pv ? pv : v;
                    v = (up == lower) ? mn : mx;
                }
            }
            unsigned prev = (unsigned)__shfl_up((int)v, 1);
            bool lead = (l < deg) && (l == 0 || v != prev);
            unsigned long long L = __ballot(lead);
            if (lead) {
                unsigned long long gt = (l >= 63) ? 0ULL : (L & (~0ULL << (l + 1)));
                int nxt = gt ? __builtin_ctzll(gt) : deg;
                int count = nxt - l;
                unsigned long long below = (l == 0) ? 0ULL : (L & ((1ULL << l) - 1ULL));
                int rank = __builtin_popcountll(below);
                mcsr[(size_t)g * E_PER + rsg + rank] =
                    ((unsigned)count << 16) | (v & 0xFFFFu);
            }
            if (l == 0) {
                rowlen[g * NNODE + r] = __builtin_popcountll(L);
                rowstart[g * NNODE + r] = rsg;
            }
        } else if (l == 0) {
            // rare slow path: serial insertion sort + merge
            for (int i = 1; i < deg; ++i) {
                unsigned short key = ssrcL[ls + i];
                int j = i - 1;
                while (j >= 0 && ssrcL[ls + j] > key) { ssrcL[ls + j + 1] = ssrcL[ls + j]; --j; }
                ssrcL[ls + j + 1] = key;
            }
            int m = 0, i = 0;
            while (i < deg) {
                int s0 = ssrcL[ls + i]; int c = 1;
                while (i + c < deg && ssrcL[ls + i + c] == s0) ++c;
                mcsr[(size_t)g * E_PER + rsg + m] = ((unsigned)c << 16) | (unsigned)s0;
                ++m; i += c;
            }
            rowlen[g * NNODE + r] = m;
            rowstart[g * NNODE + r] = rsg;
        }
    }
}

// ======================= K1: omics encoder =======================
__global__ __launch_bounds__(256) void enc_kernel(
    const float* __restrict__ omics, const float* __restrict__ w,
    const float* __restrict__ b, const float* __restrict__ rot,
    const float* __restrict__ gamma, const float* __restrict__ beta,
    const float* __restrict__ mean, const float* __restrict__ var,
    float* __restrict__ x)
{
    int o = blockIdx.x;
    __shared__ float Wl[D_IN * HDIM];       // 32 KB
    __shared__ float Om[G * 132];           // 33 KB
    int t = threadIdx.x;
    for (int i = t; i < D_IN * HDIM / 4; i += 256)
        ((float4*)Wl)[i] = ((const float4*)(w + (size_t)o * D_IN * HDIM))[i];
    for (int i = t; i < G * (D_IN / 4); i += 256) {
        int g = i >> 5, dq = i & 31;
        *((float4*)(Om + g * 132) + dq) =
            ((const float4*)(omics + ((size_t)g * NNODE + o) * D_IN))[dq];
    }
    __syncthreads();

    int w4 = t >> 6, l = t & 63;
    int cq = l & 15, gsub = l >> 4;
    int gbase = w4 * 4 + gsub;
    float4 acc[4];
    #pragma unroll
    for (int gi = 0; gi < 4; ++gi) acc[gi] = make_float4(0.f, 0.f, 0.f, 0.f);

    for (int d = 0; d < D_IN; ++d) {
        float4 wv = *(const float4*)&Wl[d * 64 + cq * 4];
        #pragma unroll
        for (int gi = 0; gi < 4; ++gi) {
            float ov = Om[(gi * 16 + gbase) * 132 + d];
            acc[gi].x = fmaf(ov, wv.x, acc[gi].x);
            acc[gi].y = fmaf(ov, wv.y, acc[gi].y);
            acc[gi].z = fmaf(ov, wv.z, acc[gi].z);
            acc[gi].w = fmaf(ov, wv.w, acc[gi].w);
        }
    }

    float4 bv = ((const float4*)b)[o * 16 + cq];
    float4 rv = ((const float4*)rot)[o * 16 + cq];
    float4 mv = ((const float4*)mean)[o * 16 + cq];
    float4 vv = ((const float4*)var)[o * 16 + cq];
    float4 gv = ((const float4*)gamma)[o * 16 + cq];
    float4 be = ((const float4*)beta)[o * 16 + cq];
    float4 sc, kk;
    sc.x = cosf(rv.x) + sinf(rv.x); sc.y = cosf(rv.y) + sinf(rv.y);
    sc.z = cosf(rv.z) + sinf(rv.z); sc.w = cosf(rv.w) + sinf(rv.w);
    kk.x = gv.x * rsqrtf(vv.x + BN_EPS); kk.y = gv.y * rsqrtf(vv.y + BN_EPS);
    kk.z = gv.z * rsqrtf(vv.z + BN_EPS); kk.w = gv.w * rsqrtf(vv.w + BN_EPS);

    #pragma unroll
    for (int gi = 0; gi < 4; ++gi) {
        int g = gi * 16 + gbase;
        float4 v;
        v.x = fmaxf((acc[gi].x + bv.x) * sc.x, 0.f);
        v.y = fmaxf((acc[gi].y + bv.y) * sc.y, 0.f);
        v.z = fmaxf((acc[gi].z + bv.z) * sc.z, 0.f);
        v.w = fmaxf((acc[gi].w + bv.w) * sc.w, 0.f);
        v.x = (v.x - mv.x) * kk.x + be.x;
        v.y = (v.y - mv.y) * kk.y + be.y;
        v.z = (v.z - mv.z) * kk.z + be.z;
        v.w = (v.w - mv.w) * kk.w + be.w;
        *(float4*)&x[((size_t)(g * NNODE + o)) * 64 + cq * 4] = v;
    }
}

// ======================= K2: GAT1 linear =========================
__global__ __launch_bounds__(256) void gat1_lin(
    const float* __restrict__ x, const float* __restrict__ W,
    const float* __restrict__ att_s, const float* __restrict__ att_d,
    float* __restrict__ h1, float* __restrict__ as1, float* __restrict__ ad1)
{
    int blk = blockIdx.x;
    __shared__ float Xl[64 * 65];
    __shared__ float Wl[64 * 256];
    int t = threadIdx.x;
    int node0 = blk * 64;
    for (int i = t; i < 64 * 64; i += 256) {
        int nl = i >> 6, k = i & 63;
        Xl[nl * 65 + k] = x[(size_t)node0 * HDIM + i];
    }
    for (int i = t; i < 64 * 256 / 4; i += 256)
        ((float4*)Wl)[i] = ((const float4*)W)[i];
    __syncthreads();

    int w = t >> 6, l = t & 63;
    int nsub = l >> 2, csel = l & 3;
    float4 acc[4][4];
    #pragma unroll
    for (int ni = 0; ni < 4; ++ni)
        #pragma unroll
        for (int cj = 0; cj < 4; ++cj) acc[ni][cj] = make_float4(0.f, 0.f, 0.f, 0.f);

    for (int k = 0; k < 64; ++k) {
        float4 wv[4];
        #pragma unroll
        for (int cj = 0; cj < 4; ++cj)
            wv[cj] = *(const float4*)&Wl[k * 256 + w * 64 + cj * 16 + csel * 4];
        #pragma unroll
        for (int ni = 0; ni < 4; ++ni) {
            float xv = Xl[(ni * 16 + nsub) * 65 + k];
            #pragma unroll
            for (int cj = 0; cj < 4; ++cj) {
                acc[ni][cj].x = fmaf(xv, wv[cj].x, acc[ni][cj].x);
                acc[ni][cj].y = fmaf(xv, wv[cj].y, acc[ni][cj].y);
                acc[ni][cj].z = fmaf(xv, wv[cj].z, acc[ni][cj].z);
                acc[ni][cj].w = fmaf(xv, wv[cj].w, acc[ni][cj].w);
            }
        }
    }

    float4 as_w[4], ad_w[4];
    #pragma unroll
    for (int cj = 0; cj < 4; ++cj) {
        as_w[cj] = ((const float4*)att_s)[w * 16 + cj * 4 + csel];
        ad_w[cj] = ((const float4*)att_d)[w * 16 + cj * 4 + csel];
    }
    #pragma unroll
    for (int ni = 0; ni < 4; ++ni) {
        int n = ni * 16 + nsub;
        float asv = 0.f, adv = 0.f;
        #pragma unroll
        for (int cj = 0; cj < 4; ++cj) {
            asv += acc[ni][cj].x * as_w[cj].x + acc[ni][cj].y * as_w[cj].y
                 + acc[ni][cj].z * as_w[cj].z + acc[ni][cj].w * as_w[cj].w;
            adv += acc[ni][cj].x * ad_w[cj].x + acc[ni][cj].y * ad_w[cj].y
                 + acc[ni][cj].z * ad_w[cj].z + acc[ni][cj].w * ad_w[cj].w;
            *(float4*)&h1[((size_t)(node0 + n) * HEADS + w) * 64 + cj * 16 + csel * 4]
                = acc[ni][cj];
        }
        asv += __shfl_xor(asv, 1); asv += __shfl_xor(asv, 2);
        adv += __shfl_xor(adv, 1); adv += __shfl_xor(adv, 2);
        if (csel == 0) {
            as1[(node0 + n) * HEADS + w] = asv;
            ad1[(node0 + n) * HEADS + w] = adv;
        }
    }
}

// ======================= K3: GAT1 edge via merged-CSR MFMA =======
__global__ __launch_bounds__(512) void gat1_edge_mfma(
    const float* __restrict__ h1, const float* __restrict__ as1,
    const float* __restrict__ ad1, const unsigned int* __restrict__ mcsr,
    const int* __restrict__ rowstart, const int* __restrict__ rowlen,
    const float* __restrict__ bias1, float* __restrict__ x2)
{
    int g = blockIdx.x, head = blockIdx.y, by = blockIdx.z;
    __shared__ unsigned short ht[64 * NNODE];   // 32 KB bf16 H^T, oct^(c&31)
    __shared__ unsigned short Mb[64 * NNODE];   // 32 KB bf16 M, oct^(row&7)
    __shared__ float asl[NNODE], adl[NNODE], u1[NNODE], u2[NNODE];
    __shared__ float v1[NNODE], v2[NNODE], den[64];
    __shared__ float wred[8];
    int t = threadIdx.x;

    float va = -1e30f, vd = 0.f;
    if (t < NNODE) {
        va = as1[(g * NNODE + t) * HEADS + head];
        vd = ad1[(g * NNODE + t) * HEADS + head];
        asl[t] = va; adl[t] = vd;
    }
    {
        float mv = va;
        #pragma unroll
        for (int d = 32; d; d >>= 1) mv = fmaxf(mv, __shfl_xor(mv, d));
        if ((t & 63) == 0) wred[t >> 6] = mv;
    }
    __syncthreads();
    if (t < NNODE) {
        float M = fmaxf(fmaxf(wred[0], wred[1]), fmaxf(wred[2], wred[3]));
        float mt = lrelu02(M + vd);
        v1[t] = __expf(vd - mt);
        v2[t] = __expf(0.2f * vd - mt);
        u1[t] = __expf(va);
        u2[t] = __expf(0.2f * va);
    }
    for (int i = t; i < NNODE * 16; i += 512) {
        int s = i >> 4, cq = i & 15;
        float4 hv = ((const float4*)h1)[((size_t)(g * NNODE + s) * HEADS + head) * 16 + cq];
        int c0 = cq * 4;
        ht[(c0 + 0) * 256 + (((s >> 3) ^ ((c0 + 0) & 31)) << 3) + (s & 7)] = f2bf(hv.x);
        ht[(c0 + 1) * 256 + (((s >> 3) ^ ((c0 + 1) & 31)) << 3) + (s & 7)] = f2bf(hv.y);
        ht[(c0 + 2) * 256 + (((s >> 3) ^ ((c0 + 2) & 31)) << 3) + (s & 7)] = f2bf(hv.z);
        ht[(c0 + 3) * 256 + (((s >> 3) ^ ((c0 + 3) & 31)) << 3) + (s & 7)] = f2bf(hv.w);
    }
    __syncthreads();

    int w = t >> 6, l = t & 63;
    int lrow = l & 15, lk = l >> 4;

    for (int qi = 0; qi < 2; ++qi) {
        int q = by * 2 + qi;
        int r0 = q * 64;
        float4 z4 = make_float4(0.f, 0.f, 0.f, 0.f);
        for (int i = t; i < 2048; i += 512) ((float4*)Mb)[i] = z4;
        __syncthreads();
        for (int ri = w; ri < 64; ri += 8) {
            int d = r0 + ri;
            int rs = rowstart[g * NNODE + d], len = rowlen[g * NNODE + d];
            float adv = adl[d], vd1 = v1[d], vd2 = v2[d];
            float ss = 0.f;
            for (int e0 = 0; e0 < len; e0 += 64) {
                int e = e0 + l;
                float p = 0.f;
                if (e < len) {
                    unsigned ent = mcsr[(size_t)g * E_PER + rs + e];
                    int s = ent & 0xFFFFu;
                    float c = (float)(ent >> 16);
                    float z = asl[s] + adv;
                    p = c * (z > 0.f ? u1[s] * vd1 : u2[s] * vd2);
                    Mb[ri * 256 + ((((s >> 3) ^ (ri & 7)) << 3) | (s & 7))] = f2bf(p);
                }
                ss += p;
            }
            #pragma unroll
            for (int m = 1; m < 64; m <<= 1) ss += __shfl_xor(ss, m);
            if (l == 0) den[ri] = ss;
        }
        __syncthreads();
        int mt = w & 3, nb = (w >> 2) * 2;
        f32x4 acc0 = {0.f, 0.f, 0.f, 0.f};
        f32x4 acc1 = {0.f, 0.f, 0.f, 0.f};
        int ar = mt * 16 + lrow;
        int c0 = nb * 16 + lrow, c1 = c0 + 16;
        #pragma unroll
        for (int kb = 0; kb < 8; ++kb) {
            int oct = kb * 4 + lk;
            bf16x8 a = *(const bf16x8*)&Mb[ar * 256 + ((oct ^ (ar & 7)) << 3)];
            bf16x8 b0 = *(const bf16x8*)&ht[c0 * 256 + ((oct ^ (c0 & 31)) << 3)];
            bf16x8 b1 = *(const bf16x8*)&ht[c1 * 256 + ((oct ^ (c1 & 31)) << 3)];
            acc0 = __builtin_amdgcn_mfma_f32_16x16x32_bf16(a, b0, acc0, 0, 0, 0);
            acc1 = __builtin_amdgcn_mfma_f32_16x16x32_bf16(a, b1, acc1, 0, 0, 0);
        }
        #pragma unroll
        for (int r = 0; r < 4; ++r) {
            int rl = mt * 16 + lk * 4 + r;
            int d = r0 + rl;
            float inv = 1.f / (den[rl] + 1e-16f);
            float o0 = acc0[r] * inv + bias1[head * 64 + c0];
            float o1 = acc1[r] * inv + bias1[head * 64 + c1];
            o0 = o0 > 0.f ? o0 : expm1f(o0);
            o1 = o1 > 0.f ? o1 : expm1f(o1);
            size_t ob = (size_t)(g * NNODE + d) * 256 + head * 64;
            x2[ob + c0] = o0;
            x2[ob + c1] = o1;
        }
        __syncthreads();
    }
}

// ======================= K4: GAT2 linear =========================
__global__ __launch_bounds__(256) void gat2_lin(
    const float* __restrict__ x2, const float* __restrict__ W,
    const float* __restrict__ att_s, const float* __restrict__ att_d,
    float* __restrict__ h2, float* __restrict__ as2, float* __restrict__ ad2)
{
    int blk = blockIdx.x;
    __shared__ float Xl[64 * 260];
    __shared__ float Wl[256 * 64];
    int t = threadIdx.x;
    int node0 = blk * 64;
    for (int i = t; i < 64 * 64; i += 256) {
        int nl = i >> 6, kq = i & 63;
        *((float4*)(Xl + nl * 260) + kq) =
            ((const float4*)(x2 + (size_t)(node0 + nl) * 256))[kq];
    }
    for (int i = t; i < 256 * 64 / 4; i += 256)
        ((float4*)Wl)[i] = ((const float4*)W)[i];
    __syncthreads();

    int w = t >> 6, l = t & 63;
    int cq = l & 15, nsub = l >> 4;
    float4 acc[4];
    #pragma unroll
    for (int ni = 0; ni < 4; ++ni) acc[ni] = make_float4(0.f, 0.f, 0.f, 0.f);

    for (int k0 = 0; k0 < 256; k0 += 4) {
        float4 wv[4];
        #pragma unroll
        for (int kk = 0; kk < 4; ++kk)
            wv[kk] = *(const float4*)&Wl[(k0 + kk) * 64 + cq * 4];
        #pragma unroll
        for (int ni = 0; ni < 4; ++ni) {
            float4 xq = *(const float4*)&Xl[(w * 16 + ni * 4 + nsub) * 260 + k0];
            acc[ni].x = fmaf(xq.x, wv[0].x, acc[ni].x);
            acc[ni].y = fmaf(xq.x, wv[0].y, acc[ni].y);
            acc[ni].z = fmaf(xq.x, wv[0].z, acc[ni].z);
            acc[ni].w = fmaf(xq.x, wv[0].w, acc[ni].w);
            acc[ni].x = fmaf(xq.y, wv[1].x, acc[ni].x);
            acc[ni].y = fmaf(xq.y, wv[1].y, acc[ni].y);
            acc[ni].z = fmaf(xq.y, wv[1].z, acc[ni].z);
            acc[ni].w = fmaf(xq.y, wv[1].w, acc[ni].w);
            acc[ni].x = fmaf(xq.z, wv[2].x, acc[ni].x);
            acc[ni].y = fmaf(xq.z, wv[2].y, acc[ni].y);
            acc[ni].z = fmaf(xq.z, wv[2].z, acc[ni].z);
            acc[ni].w = fmaf(xq.z, wv[2].w, acc[ni].w);
            acc[ni].x = fmaf(xq.w, wv[3].x, acc[ni].x);
            acc[ni].y = fmaf(xq.w, wv[3].y, acc[ni].y);
            acc[ni].z = fmaf(xq.w, wv[3].z, acc[ni].z);
            acc[ni].w = fmaf(xq.w, wv[3].w, acc[ni].w);
        }
    }

    float4 as_w = ((const float4*)att_s)[cq];
    float4 ad_w = ((const float4*)att_d)[cq];
    #pragma unroll
    for (int ni = 0; ni < 4; ++ni) {
        int n = w * 16 + ni * 4 + nsub;
        float asv = acc[ni].x * as_w.x + acc[ni].y * as_w.y
                  + acc[ni].z * as_w.z + acc[ni].w * as_w.w;
        float adv = acc[ni].x * ad_w.x + acc[ni].y * ad_w.y
                  + acc[ni].z * ad_w.z + acc[ni].w * ad_w.w;
        #pragma unroll
        for (int m = 1; m <= 8; m <<= 1) {
            asv += __shfl_xor(asv, m);
            adv += __shfl_xor(adv, m);
        }
        *(float4*)&h2[(size_t)(node0 + n) * 64 + cq * 4] = acc[ni];
        if (cq == 0) { as2[node0 + n] = asv; ad2[node0 + n] = adv; }
    }
}

// ======================= K5: GAT2 edge MFMA + partial pool =======
__global__ __launch_bounds__(512) void gat2_edge_mfma(
    const float* __restrict__ h2, const float* __restrict__ as2,
    const float* __restrict__ ad2, const unsigned int* __restrict__ mcsr,
    const int* __restrict__ rowstart, const int* __restrict__ rowlen,
    float* __restrict__ pl8)
{
    int g = blockIdx.x, by = blockIdx.y;
    __shared__ unsigned short ht[64 * NNODE];   // 32 KB
    __shared__ unsigned short Mb[32 * NNODE];   // 16 KB
    __shared__ float asl[NNODE], adl[NNODE], u1[NNODE], u2[NNODE];
    __shared__ float v1[NNODE], v2[NNODE], den[32];
    __shared__ float wred[8];
    __shared__ float pool[64];
    int t = threadIdx.x;

    float va = -1e30f, vd = 0.f;
    if (t < NNODE) {
        va = as2[g * NNODE + t];
        vd = ad2[g * NNODE + t];
        asl[t] = va; adl[t] = vd;
    }
    if (t < 64) pool[t] = 0.f;
    {
        float mv = va;
        #pragma unroll
        for (int d = 32; d; d >>= 1) mv = fmaxf(mv, __shfl_xor(mv, d));
        if ((t & 63) == 0) wred[t >> 6] = mv;
    }
    __syncthreads();
    if (t < NNODE) {
        float M = fmaxf(fmaxf(wred[0], wred[1]), fmaxf(wred[2], wred[3]));
        float mt = lrelu02(M + vd);
        v1[t] = __expf(vd - mt);
        v2[t] = __expf(0.2f * vd - mt);
        u1[t] = __expf(va);
        u2[t] = __expf(0.2f * va);
    }
    for (int i = t; i < NNODE * 16; i += 512) {
        int s = i >> 4, cq = i & 15;
        float4 hv = ((const float4*)h2)[(size_t)g * NNODE * 16 + i];
        int c0 = cq * 4;
        ht[(c0 + 0) * 256 + (((s >> 3) ^ ((c0 + 0) & 31)) << 3) + (s & 7)] = f2bf(hv.x);
        ht[(c0 + 1) * 256 + (((s >> 3) ^ ((c0 + 1) & 31)) << 3) + (s & 7)] = f2bf(hv.y);
        ht[(c0 + 2) * 256 + (((s >> 3) ^ ((c0 + 2) & 31)) << 3) + (s & 7)] = f2bf(hv.z);
        ht[(c0 + 3) * 256 + (((s >> 3) ^ ((c0 + 3) & 31)) << 3) + (s & 7)] = f2bf(hv.w);
    }
    float4 z4 = make_float4(0.f, 0.f, 0.f, 0.f);
    for (int i = t; i < 1024; i += 512) ((float4*)Mb)[i] = z4;
    __syncthreads();

    int w = t >> 6, l = t & 63;
    int lrow = l & 15, lk = l >> 4;
    int r0 = by * 32;

    for (int ri = w; ri < 32; ri += 8) {
        int d = r0 + ri;
        int rs = rowstart[g * NNODE + d], len = rowlen[g * NNODE + d];
        float adv = adl[d], vd1 = v1[d], vd2 = v2[d];
        float ss = 0.f;
        for (int e0 = 0; e0 < len; e0 += 64) {
            int e = e0 + l;
            float p = 0.f;
            if (e < len) {
                unsigned ent = mcsr[(size_t)g * E_PER + rs + e];
                int s = ent & 0xFFFFu;
                float c = (float)(ent >> 16);
                float z = asl[s] + adv;
                p = c * (z > 0.f ? u1[s] * vd1 : u2[s] * vd2);
                Mb[ri * 256 + ((((s >> 3) ^ (ri & 7)) << 3) | (s & 7))] = f2bf(p);
            }
            ss += p;
        }
        #pragma unroll
        for (int m = 1; m < 64; m <<= 1) ss += __shfl_xor(ss, m);
        if (l == 0) den[ri] = ss;
    }
    __syncthreads();

    int mt = w & 1, nt = w >> 1;
    f32x4 acc = {0.f, 0.f, 0.f, 0.f};
    int ar = mt * 16 + lrow;
    int c = nt * 16 + lrow;
    #pragma unroll
    for (int kb = 0; kb < 8; ++kb) {
        int oct = kb * 4 + lk;
        bf16x8 a = *(const bf16x8*)&Mb[ar * 256 + ((oct ^ (ar & 7)) << 3)];
        bf16x8 b = *(const bf16x8*)&ht[c * 256 + ((oct ^ (c & 31)) << 3)];
        acc = __builtin_amdgcn_mfma_f32_16x16x32_bf16(a, b, acc, 0, 0, 0);
    }
    float ps = 0.f;
    #pragma unroll
    for (int r = 0; r < 4; ++r) {
        int rl = mt * 16 + lk * 4 + r;
        ps = fmaf(acc[r], 1.f / (den[rl] + 1e-16f), ps);
    }
    ps += __shfl_xor(ps, 16);
    ps += __shfl_xor(ps, 32);
    if (l < 16) atomicAdd(&pool[nt * 16 + lrow], ps);
    __syncthreads();
    if (t < 64) pl8[(size_t)(g * 8 + by) * 64 + t] = pool[t];
}

// ======================= K6: pool-combine + classifier ===========
__global__ __launch_bounds__(64) void cls_kernel(
    const float* __restrict__ pl8, const float* __restrict__ bias2,
    const float* __restrict__ w1, const float* __restrict__ b1,
    const float* __restrict__ w2, const float* __restrict__ b2,
    float* __restrict__ outv, float* __restrict__ pooled)
{
    int g = blockIdx.x, c = threadIdx.x;
    float po = 0.f;
    #pragma unroll
    for (int q = 0; q < 8; ++q) po += pl8[(size_t)(g * 8 + q) * 64 + c];
    po = po * (1.f / 256.f) + bias2[c];
    pooled[g * 64 + c] = po;
    __shared__ float poL[64];
    poL[c] = po;
    __syncthreads();
    float acc = b1[c];
    for (int k = 0; k < 64; ++k) acc = fmaf(poL[k], w1[k * 64 + c], acc);
    acc = fmaxf(acc, 0.f);
    float contrib = acc * w2[c];
    #pragma unroll
    for (int d = 32; d; d >>= 1) contrib += __shfl_xor(contrib, d);
    if (c == 0) outv[g] = 1.f / (1.f + __expf(-contrib));
}

extern "C" void kernel_launch(void* const* d_in, const int* in_sizes, int n_in,
                              void* d_out, int out_size, void* d_ws, size_t ws_size,
                              hipStream_t stream) {
    const float* omics   = (const float*)d_in[0];
    const float* w_omics = (const float*)d_in[1];
    const float* b_omics = (const float*)d_in[2];
    const float* rot     = (const float*)d_in[3];
    const float* bn_g    = (const float*)d_in[4];
    const float* bn_b    = (const float*)d_in[5];
    const float* bn_m    = (const float*)d_in[6];
    const float* bn_v    = (const float*)d_in[7];
    const float* gat1_w  = (const float*)d_in[8];
    const float* att_s1  = (const float*)d_in[9];
    const float* att_d1  = (const float*)d_in[10];
    const float* bias1   = (const float*)d_in[11];
    const float* gat2_w  = (const float*)d_in[12];
    const float* att_s2  = (const float*)d_in[13];
    const float* att_d2  = (const float*)d_in[14];
    const float* bias2   = (const float*)d_in[15];
    const float* cls_w1  = (const float*)d_in[16];
    const float* cls_b1  = (const float*)d_in[17];
    const float* cls_w2  = (const float*)d_in[18];
    const float* cls_b2  = (const float*)d_in[19];
    const int*   eidx    = (const int*)d_in[20];

    float* ws = (float*)d_ws;
    size_t o_x    = 0;
    size_t o_h1   = o_x  + (size_t)NUM_NODES * HDIM;
    size_t o_as1  = o_h1 + (size_t)NUM_NODES * HEADS * 64;
    size_t o_ad1  = o_as1 + (size_t)NUM_NODES * HEADS;
    size_t o_x2   = o_ad1 + (size_t)NUM_NODES * HEADS;
    size_t o_h2   = o_x2 + (size_t)NUM_NODES * HEADS * 64;
    size_t o_as2  = o_h2 + (size_t)NUM_NODES * 64;
    size_t o_ad2  = o_as2 + (size_t)NUM_NODES;
    size_t o_pl8  = o_ad2 + (size_t)NUM_NODES;
    size_t o_mcsr = o_pl8 + (size_t)G * 8 * 64;
    size_t o_rs   = o_mcsr + (size_t)E_TOTAL;        // mcsr u32, 1 f32 unit each
    size_t o_rl   = o_rs + (size_t)NUM_NODES;

    float* x   = ws + o_x;
    float* h1  = ws + o_h1;
    float* as1 = ws + o_as1;
    float* ad1 = ws + o_ad1;
    float* x2  = ws + o_x2;
    float* h2  = ws + o_h2;
    float* as2 = ws + o_as2;
    float* ad2 = ws + o_ad2;
    float* pl8 = ws + o_pl8;
    unsigned int* mcsr = (unsigned int*)(ws + o_mcsr);
    int* rowstart_ws = (int*)(ws + o_rs);
    int* rowlen_ws   = (int*)(ws + o_rl);

    float* outv   = (float*)d_out;        // [64]
    float* pooled = (float*)d_out + G;    // [64*64]

    csr_build<<<dim3(G, CSR_SPLIT), 512, 0, stream>>>(eidx, mcsr, rowstart_ws, rowlen_ws);
    enc_kernel<<<256, 256, 0, stream>>>(omics, w_omics, b_omics, rot,
                                        bn_g, bn_b, bn_m, bn_v, x);
    gat1_lin<<<256, 256, 0, stream>>>(x, gat1_w, att_s1, att_d1, h1, as1, ad1);
    gat1_edge_mfma<<<dim3(G, HEADS, 2), 512, 0, stream>>>(
        h1, as1, ad1, mcsr, rowstart_ws, rowlen_ws, bias1, x2);
    gat2_lin<<<256, 256, 0, stream>>>(x2, gat2_w, att_s2, att_d2, h2, as2, ad2);
    gat2_edge_mfma<<<dim3(G, 8), 512, 0, stream>>>(
        h2, as2, ad2, mcsr, rowstart_ws, rowlen_ws, pl8);
    cls_kernel<<<G, 64, 0, stream>>>(pl8, bias2, cls_w1, cls_b1, cls_w2, cls_b2,
                                     outv, pooled);
}

// Round 8
// 101.962 us; speedup vs baseline: 1.3424x; 1.0928x over previous
//
#include <hip/hip_runtime.h>
#include <hip/hip_bf16.h>
#include <math.h>

#define G 64
#define NNODE 256      // nodes per graph (= O)
#define D_IN 128
#define HDIM 64
#define HEADS 4
#define E_PER 8192
#define NUM_NODES (G * NNODE)
#define E_TOTAL (G * E_PER)
#define BN_EPS 1e-5f

#define CSR_SPLIT 8
#define CSR_ROWS (NNODE / CSR_SPLIT)
#define CSR_BUF 2176

typedef __attribute__((ext_vector_type(8))) short bf16x8;
typedef __attribute__((ext_vector_type(4))) float f32x4;

__device__ __forceinline__ float lrelu02(float x) { return x > 0.f ? x : 0.2f * x; }
__device__ __forceinline__ unsigned short f2bf(float f) {
    unsigned u = __float_as_uint(f);
    return (unsigned short)((u + 0x7FFFu + ((u >> 16) & 1u)) >> 16);
}
__device__ __forceinline__ unsigned long long pk4(float a, float b, float c, float d) {
    return (unsigned long long)f2bf(a)
         | ((unsigned long long)f2bf(b) << 16)
         | ((unsigned long long)f2bf(c) << 32)
         | ((unsigned long long)f2bf(d) << 48);
}

// ======================= K-1: weight transpose to bf16 ===========
__global__ __launch_bounds__(256) void prep_w(
    const float* __restrict__ w1, const float* __restrict__ w2,
    unsigned short* __restrict__ wt1, unsigned short* __restrict__ wt2)
{
    int t = blockIdx.x * 256 + threadIdx.x;      // 64 blocks -> 16384
    int c = t >> 6, k = t & 63;
    wt1[c * 64 + k] = f2bf(w1[k * 256 + c]);     // [c 256][k 64]
    int c2 = t >> 8, k2 = t & 255;
    wt2[c2 * 256 + k2] = f2bf(w2[k2 * 64 + c2]); // [c 64][k 256]
}

// ======================= K0: merged+sorted CSR build =============
__global__ __launch_bounds__(512) void csr_build(
    const int* __restrict__ eidx, unsigned int* __restrict__ mcsr,
    int* __restrict__ rowstart, int* __restrict__ rowlen)
{
    int g = blockIdx.x, by = blockIdx.y;
    __shared__ unsigned short ssrcL[CSR_BUF];
    __shared__ int cnt[NNODE], offv[NNODE + 1];
    __shared__ int cur[CSR_ROWS];
    __shared__ int wsum[8];
    int t = threadIdx.x;
    if (t < NNODE) cnt[t] = 0;
    __syncthreads();

    const int* srcp = eidx + (size_t)g * E_PER;
    const int* dstp = eidx + E_TOTAL + (size_t)g * E_PER;
    int base = g * NNODE;

    for (int e = t; e < E_PER; e += 512) atomicAdd(&cnt[dstp[e] - base], 1);
    __syncthreads();

    int vincl = (t < NNODE) ? cnt[t] : 0;
    #pragma unroll
    for (int d = 1; d < 64; d <<= 1) {
        int o = __shfl_up(vincl, d);
        if ((t & 63) >= d) vincl += o;
    }
    if (t < NNODE && (t & 63) == 63) wsum[t >> 6] = vincl;
    __syncthreads();
    if (t < NNODE) {
        int w = t >> 6;
        int add = 0;
        if (w > 0) add += wsum[0];
        if (w > 1) add += wsum[1];
        if (w > 2) add += wsum[2];
        offv[t] = vincl - cnt[t] + add;
    }
    if (t == 0) offv[NNODE] = E_PER;
    __syncthreads();

    int r0 = by * CSR_ROWS;
    int lb = offv[r0];
    if (t < CSR_ROWS) cur[t] = offv[r0 + t] - lb;
    __syncthreads();

    for (int e = t; e < E_PER; e += 512) {
        int d = dstp[e] - base - r0;
        if ((unsigned)d < CSR_ROWS) {
            int s = srcp[e] - base;
            int pos = atomicAdd(&cur[d], 1);
            ssrcL[pos] = (unsigned short)s;
        }
    }
    __syncthreads();

    int w = t >> 6, l = t & 63;
    for (int ri = w; ri < CSR_ROWS; ri += 8) {
        int r = r0 + ri;
        int rsg = offv[r], deg = offv[r + 1] - rsg;
        int ls = rsg - lb;
        if (deg <= 64) {
            unsigned v = (l < deg) ? (unsigned)ssrcL[ls + l] : 0xFFFFu;
            #pragma unroll
            for (int k = 2; k <= 64; k <<= 1) {
                #pragma unroll
                for (int j = k >> 1; j > 0; j >>= 1) {
                    unsigned pv = (unsigned)__shfl_xor((int)v, j);
                    bool up = ((l & k) == 0);
                    bool lower = ((l & j) == 0);
                    unsigned mn = v < pv ? v : pv;
                    unsigned mx = v < pv ? pv : v;
                    v = (up == lower) ? mn : mx;
                }
            }
            unsigned prev = (unsigned)__shfl_up((int)v, 1);
            bool lead = (l < deg) && (l == 0 || v != prev);
            unsigned long long L = __ballot(lead);
            if (lead) {
                unsigned long long gt = (l >= 63) ? 0ULL : (L & (~0ULL << (l + 1)));
                int nxt = gt ? __builtin_ctzll(gt) : deg;
                int count = nxt - l;
                unsigned long long below = (l == 0) ? 0ULL : (L & ((1ULL << l) - 1ULL));
                int rank = __builtin_popcountll(below);
                mcsr[(size_t)g * E_PER + rsg + rank] =
                    ((unsigned)count << 16) | (v & 0xFFFFu);
            }
            if (l == 0) {
                rowlen[g * NNODE + r] = __builtin_popcountll(L);
                rowstart[g * NNODE + r] = rsg;
            }
        } else if (l == 0) {
            for (int i = 1; i < deg; ++i) {
                unsigned short key = ssrcL[ls + i];
                int j = i - 1;
                while (j >= 0 && ssrcL[ls + j] > key) { ssrcL[ls + j + 1] = ssrcL[ls + j]; --j; }
                ssrcL[ls + j + 1] = key;
            }
            int m = 0, i = 0;
            while (i < deg) {
                int s0 = ssrcL[ls + i]; int c = 1;
                while (i + c < deg && ssrcL[ls + i + c] == s0) ++c;
                mcsr[(size_t)g * E_PER + rsg + m] = ((unsigned)c << 16) | (unsigned)s0;
                ++m; i += c;
            }
            rowlen[g * NNODE + r] = m;
            rowstart[g * NNODE + r] = rsg;
        }
    }
}

// ======================= K1: omics encoder (f32 -> bf16 out) =====
__global__ __launch_bounds__(256) void enc_kernel(
    const float* __restrict__ omics, const float* __restrict__ w,
    const float* __restrict__ b, const float* __restrict__ rot,
    const float* __restrict__ gamma, const float* __restrict__ beta,
    const float* __restrict__ mean, const float* __restrict__ var,
    unsigned short* __restrict__ xb)
{
    int o = blockIdx.x;
    __shared__ float Wl[D_IN * HDIM];
    __shared__ float Om[G * 132];
    int t = threadIdx.x;
    for (int i = t; i < D_IN * HDIM / 4; i += 256)
        ((float4*)Wl)[i] = ((const float4*)(w + (size_t)o * D_IN * HDIM))[i];
    for (int i = t; i < G * (D_IN / 4); i += 256) {
        int g = i >> 5, dq = i & 31;
        *((float4*)(Om + g * 132) + dq) =
            ((const float4*)(omics + ((size_t)g * NNODE + o) * D_IN))[dq];
    }
    __syncthreads();

    int w4 = t >> 6, l = t & 63;
    int cq = l & 15, gsub = l >> 4;
    int gbase = w4 * 4 + gsub;
    float4 acc[4];
    #pragma unroll
    for (int gi = 0; gi < 4; ++gi) acc[gi] = make_float4(0.f, 0.f, 0.f, 0.f);

    for (int d = 0; d < D_IN; ++d) {
        float4 wv = *(const float4*)&Wl[d * 64 + cq * 4];
        #pragma unroll
        for (int gi = 0; gi < 4; ++gi) {
            float ov = Om[(gi * 16 + gbase) * 132 + d];
            acc[gi].x = fmaf(ov, wv.x, acc[gi].x);
            acc[gi].y = fmaf(ov, wv.y, acc[gi].y);
            acc[gi].z = fmaf(ov, wv.z, acc[gi].z);
            acc[gi].w = fmaf(ov, wv.w, acc[gi].w);
        }
    }

    float4 bv = ((const float4*)b)[o * 16 + cq];
    float4 rv = ((const float4*)rot)[o * 16 + cq];
    float4 mv = ((const float4*)mean)[o * 16 + cq];
    float4 vv = ((const float4*)var)[o * 16 + cq];
    float4 gv = ((const float4*)gamma)[o * 16 + cq];
    float4 be = ((const float4*)beta)[o * 16 + cq];
    float4 sc, kk;
    sc.x = cosf(rv.x) + sinf(rv.x); sc.y = cosf(rv.y) + sinf(rv.y);
    sc.z = cosf(rv.z) + sinf(rv.z); sc.w = cosf(rv.w) + sinf(rv.w);
    kk.x = gv.x * rsqrtf(vv.x + BN_EPS); kk.y = gv.y * rsqrtf(vv.y + BN_EPS);
    kk.z = gv.z * rsqrtf(vv.z + BN_EPS); kk.w = gv.w * rsqrtf(vv.w + BN_EPS);

    #pragma unroll
    for (int gi = 0; gi < 4; ++gi) {
        int g = gi * 16 + gbase;
        float4 v;
        v.x = fmaxf((acc[gi].x + bv.x) * sc.x, 0.f);
        v.y = fmaxf((acc[gi].y + bv.y) * sc.y, 0.f);
        v.z = fmaxf((acc[gi].z + bv.z) * sc.z, 0.f);
        v.w = fmaxf((acc[gi].w + bv.w) * sc.w, 0.f);
        v.x = (v.x - mv.x) * kk.x + be.x;
        v.y = (v.y - mv.y) * kk.y + be.y;
        v.z = (v.z - mv.z) * kk.z + be.z;
        v.w = (v.w - mv.w) * kk.w + be.w;
        *(unsigned long long*)&xb[((size_t)(g * NNODE + o)) * 64 + cq * 4] =
            pk4(v.x, v.y, v.z, v.w);
    }
}

// ======================= K2: GAT1 linear via MFMA ================
// 256 blocks x 512 thr: 64 nodes/block, N=256 (all heads), K=64.
// Outputs ht1[(g*4+head)*64+ch][s] bf16 (transposed) + as1/ad1 f32.
__global__ __launch_bounds__(512) void gat1_lin_mfma(
    const unsigned short* __restrict__ xb, const unsigned short* __restrict__ wt1,
    const float* __restrict__ att_s, const float* __restrict__ att_d,
    unsigned short* __restrict__ ht1, float* __restrict__ as1, float* __restrict__ ad1)
{
    int blk = blockIdx.x;
    int n0 = blk * 64;
    int g = n0 >> 8, soff = n0 & 255;
    __shared__ unsigned short Ab[64 * 64];     // 8 KB
    __shared__ unsigned short Bb[256 * 64];    // 32 KB
    int t = threadIdx.x;
    {   // stage A: 64 nodes x 8 k-groups (exactly 512)
        int node = t >> 3, kg = t & 7;
        bf16x8 v = *(const bf16x8*)&xb[(size_t)(n0 + node) * 64 + kg * 8];
        *(bf16x8*)&Ab[node * 64 + ((kg ^ (node & 7)) << 3)] = v;
    }
    for (int i = t; i < 2048; i += 512) {      // stage B: 256 c x 8 kg
        int c = i >> 3, kg = i & 7;
        bf16x8 v = *(const bf16x8*)&wt1[c * 64 + kg * 8];
        *(bf16x8*)&Bb[c * 64 + ((kg ^ (c & 7)) << 3)] = v;
    }
    __syncthreads();

    int w = t >> 6, l = t & 63;
    int lrow = l & 15, lk = l >> 4;
    int mt = w >> 1, hh0 = (w & 1) * 2;        // wave: m-tile mt, nt = (w&1)*8..+7
    int arow = mt * 16 + lrow;
    float asp[2][4], adp[2][4];
    #pragma unroll
    for (int hi = 0; hi < 2; ++hi)
        #pragma unroll
        for (int r = 0; r < 4; ++r) { asp[hi][r] = 0.f; adp[hi][r] = 0.f; }

    for (int ntl = 0; ntl < 8; ++ntl) {
        int nt = (w & 1) * 8 + ntl;
        int c = nt * 16 + lrow;
        f32x4 acc = {0.f, 0.f, 0.f, 0.f};
        #pragma unroll
        for (int kb = 0; kb < 2; ++kb) {
            int kg = kb * 4 + lk;
            bf16x8 a = *(const bf16x8*)&Ab[arow * 64 + ((kg ^ (arow & 7)) << 3)];
            bf16x8 b = *(const bf16x8*)&Bb[c * 64 + ((kg ^ (c & 7)) << 3)];
            acc = __builtin_amdgcn_mfma_f32_16x16x32_bf16(a, b, acc, 0, 0, 0);
        }
        int head = c >> 6, ch = c & 63;
        int sb = soff + mt * 16 + lk * 4;
        *(unsigned long long*)&ht1[(size_t)((g * HEADS + head) * 64 + ch) * 256 + sb] =
            pk4(acc[0], acc[1], acc[2], acc[3]);
        float av = att_s[c], dv = att_d[c];
        int hi = ntl >> 2;
        #pragma unroll
        for (int r = 0; r < 4; ++r) {
            asp[hi][r] = fmaf(acc[r], av, asp[hi][r]);
            adp[hi][r] = fmaf(acc[r], dv, adp[hi][r]);
        }
    }
    #pragma unroll
    for (int hi = 0; hi < 2; ++hi)
        #pragma unroll
        for (int r = 0; r < 4; ++r) {
            float a = asp[hi][r], d = adp[hi][r];
            a += __shfl_xor(a, 1); a += __shfl_xor(a, 2);
            a += __shfl_xor(a, 4); a += __shfl_xor(a, 8);
            d += __shfl_xor(d, 1); d += __shfl_xor(d, 2);
            d += __shfl_xor(d, 4); d += __shfl_xor(d, 8);
            if (lrow == 0) {
                int node = n0 + mt * 16 + lk * 4 + r;
                as1[node * HEADS + hh0 + hi] = a;
                ad1[node * HEADS + hh0 + hi] = d;
            }
        }
}

// ======================= K3: GAT1 edge via merged-CSR MFMA =======
// grid (G, HEADS), 512 thr. ht staged by copy+swizzle; x2 out bf16.
__global__ __launch_bounds__(512) void gat1_edge_mfma(
    const unsigned short* __restrict__ ht1, const float* __restrict__ as1,
    const float* __restrict__ ad1, const unsigned int* __restrict__ mcsr,
    const int* __restrict__ rowstart, const int* __restrict__ rowlen,
    const float* __restrict__ bias1, unsigned short* __restrict__ x2b)
{
    int g = blockIdx.x, head = blockIdx.y;
    __shared__ unsigned short ht[64 * 256];    // 32 KB
    __shared__ unsigned short Mb[64 * 256];    // 32 KB
    __shared__ unsigned short xs[64 * 64];     // 8 KB transpose staging
    __shared__ float asl[NNODE], adl[NNODE], u1[NNODE], u2[NNODE];
    __shared__ float v1[NNODE], v2[NNODE], den[64];
    __shared__ float wred[8];
    int t = threadIdx.x;

    float va = -1e30f, vd = 0.f;
    if (t < NNODE) {
        va = as1[(g * NNODE + t) * HEADS + head];
        vd = ad1[(g * NNODE + t) * HEADS + head];
        asl[t] = va; adl[t] = vd;
    }
    {
        float mv = va;
        #pragma unroll
        for (int d = 32; d; d >>= 1) mv = fmaxf(mv, __shfl_xor(mv, d));
        if ((t & 63) == 0) wred[t >> 6] = mv;
    }
    __syncthreads();
    if (t < NNODE) {
        float M = fmaxf(fmaxf(wred[0], wred[1]), fmaxf(wred[2], wred[3]));
        float mt = lrelu02(M + vd);
        v1[t] = __expf(vd - mt);
        v2[t] = __expf(0.2f * vd - mt);
        u1[t] = __expf(va);
        u2[t] = __expf(0.2f * va);
    }
    for (int i = t; i < 2048; i += 512) {      // stage ht: 64 c x 32 s-groups
        int c = i >> 5, sg = i & 31;
        bf16x8 v = *(const bf16x8*)&ht1[(size_t)((g * HEADS + head) * 64 + c) * 256 + sg * 8];
        *(bf16x8*)&ht[c * 256 + ((sg ^ (c & 31)) << 3)] = v;
    }
    __syncthreads();

    int w = t >> 6, l = t & 63;
    int lrow = l & 15, lk = l >> 4;
    int mt = w & 3, nb = (w >> 2) * 2;
    int ar = mt * 16 + lrow;
    int c0 = nb * 16 + lrow, c1 = c0 + 16;
    float b0v = bias1[head * 64 + c0], b1v = bias1[head * 64 + c1];

    for (int q = 0; q < 4; ++q) {
        int r0 = q * 64;
        float4 z4 = make_float4(0.f, 0.f, 0.f, 0.f);
        for (int i = t; i < 2048; i += 512) ((float4*)Mb)[i] = z4;
        __syncthreads();
        for (int ri = w; ri < 64; ri += 8) {
            int d = r0 + ri;
            int rs = rowstart[g * NNODE + d], len = rowlen[g * NNODE + d];
            float adv = adl[d], vd1 = v1[d], vd2 = v2[d];
            float ss = 0.f;
            for (int e0 = 0; e0 < len; e0 += 64) {
                int e = e0 + l;
                float p = 0.f;
                if (e < len) {
                    unsigned ent = mcsr[(size_t)g * E_PER + rs + e];
                    int s = ent & 0xFFFFu;
                    float c = (float)(ent >> 16);
                    float z = asl[s] + adv;
                    p = c * (z > 0.f ? u1[s] * vd1 : u2[s] * vd2);
                    Mb[ri * 256 + ((((s >> 3) ^ (ri & 7)) << 3) | (s & 7))] = f2bf(p);
                }
                ss += p;
            }
            #pragma unroll
            for (int m = 1; m < 64; m <<= 1) ss += __shfl_xor(ss, m);
            if (l == 0) den[ri] = ss;
        }
        __syncthreads();
        f32x4 acc0 = {0.f, 0.f, 0.f, 0.f};
        f32x4 acc1 = {0.f, 0.f, 0.f, 0.f};
        #pragma unroll
        for (int kb = 0; kb < 8; ++kb) {
            int oct = kb * 4 + lk;
            bf16x8 a = *(const bf16x8*)&Mb[ar * 256 + ((oct ^ (ar & 7)) << 3)];
            bf16x8 b0 = *(const bf16x8*)&ht[c0 * 256 + ((oct ^ (c0 & 31)) << 3)];
            bf16x8 b1 = *(const bf16x8*)&ht[c1 * 256 + ((oct ^ (c1 & 31)) << 3)];
            acc0 = __builtin_amdgcn_mfma_f32_16x16x32_bf16(a, b0, acc0, 0, 0, 0);
            acc1 = __builtin_amdgcn_mfma_f32_16x16x32_bf16(a, b1, acc1, 0, 0, 0);
        }
        #pragma unroll
        for (int r = 0; r < 4; ++r) {
            int rl = mt * 16 + lk * 4 + r;
            float inv = 1.f / (den[rl] + 1e-16f);
            float o0 = acc0[r] * inv + b0v;
            float o1 = acc1[r] * inv + b1v;
            o0 = o0 > 0.f ? o0 : expm1f(o0);
            o1 = o1 > 0.f ? o1 : expm1f(o1);
            xs[rl * 64 + c0] = f2bf(o0);
            xs[rl * 64 + c1] = f2bf(o1);
        }
        __syncthreads();
        {   // coalesced write: 64 rows x 8 groups (exactly 512)
            int row = t >> 3, cg = t & 7;
            bf16x8 v = *(const bf16x8*)&xs[row * 64 + cg * 8];
            *(bf16x8*)&x2b[(size_t)(g * NNODE + r0 + row) * 256 + head * 64 + cg * 8] = v;
        }
        __syncthreads();
    }
}

// ======================= K4: GAT2 linear via MFMA ================
// 256 blocks x 512 thr: 64 nodes/block, N=64, K=256.
__global__ __launch_bounds__(512) void gat2_lin_mfma(
    const unsigned short* __restrict__ x2b, const unsigned short* __restrict__ wt2,
    const float* __restrict__ att_s, const float* __restrict__ att_d,
    unsigned short* __restrict__ ht2, float* __restrict__ as2, float* __restrict__ ad2)
{
    int blk = blockIdx.x;
    int n0 = blk * 64;
    int g = n0 >> 8, soff = n0 & 255;
    __shared__ unsigned short Ab[64 * 256];    // 32 KB
    __shared__ unsigned short Bb[64 * 256];    // 32 KB
    __shared__ float asr[64], adr[64];
    int t = threadIdx.x;
    for (int i = t; i < 2048; i += 512) {
        int node = i >> 5, kg = i & 31;
        bf16x8 v = *(const bf16x8*)&x2b[(size_t)(n0 + node) * 256 + kg * 8];
        *(bf16x8*)&Ab[node * 256 + ((kg ^ (node & 31)) << 3)] = v;
    }
    for (int i = t; i < 2048; i += 512) {
        int c = i >> 5, kg = i & 31;
        bf16x8 v = *(const bf16x8*)&wt2[c * 256 + kg * 8];
        *(bf16x8*)&Bb[c * 256 + ((kg ^ (c & 31)) << 3)] = v;
    }
    if (t < 64) { asr[t] = 0.f; adr[t] = 0.f; }
    __syncthreads();

    int w = t >> 6, l = t & 63;
    int lrow = l & 15, lk = l >> 4;
    int mt = w & 3, nb = (w >> 2) * 2;
    int ar = mt * 16 + lrow;
    float asp[2][4], adp[2][4];
    #pragma unroll
    for (int ni = 0; ni < 2; ++ni)
        #pragma unroll
        for (int r = 0; r < 4; ++r) { asp[ni][r] = 0.f; adp[ni][r] = 0.f; }

    #pragma unroll
    for (int ni = 0; ni < 2; ++ni) {
        int c = (nb + ni) * 16 + lrow;
        f32x4 acc = {0.f, 0.f, 0.f, 0.f};
        #pragma unroll
        for (int ks = 0; ks < 8; ++ks) {
            int kg = ks * 4 + lk;
            bf16x8 a = *(const bf16x8*)&Ab[ar * 256 + ((kg ^ (ar & 31)) << 3)];
            bf16x8 b = *(const bf16x8*)&Bb[c * 256 + ((kg ^ (c & 31)) << 3)];
            acc = __builtin_amdgcn_mfma_f32_16x16x32_bf16(a, b, acc, 0, 0, 0);
        }
        int sb = soff + mt * 16 + lk * 4;
        *(unsigned long long*)&ht2[(size_t)(g * 64 + c) * 256 + sb] =
            pk4(acc[0], acc[1], acc[2], acc[3]);
        float av = att_s[c], dv = att_d[c];
        #pragma unroll
        for (int r = 0; r < 4; ++r) {
            asp[ni][r] = fmaf(acc[r], av, asp[ni][r]);
            adp[ni][r] = fmaf(acc[r], dv, adp[ni][r]);
        }
    }
    #pragma unroll
    for (int ni = 0; ni < 2; ++ni)
        #pragma unroll
        for (int r = 0; r < 4; ++r) {
            float a = asp[ni][r], d = adp[ni][r];
            a += __shfl_xor(a, 1); a += __shfl_xor(a, 2);
            a += __shfl_xor(a, 4); a += __shfl_xor(a, 8);
            d += __shfl_xor(d, 1); d += __shfl_xor(d, 2);
            d += __shfl_xor(d, 4); d += __shfl_xor(d, 8);
            if (lrow == 0) {
                int rl = mt * 16 + lk * 4 + r;
                atomicAdd(&asr[rl], a);
                atomicAdd(&adr[rl], d);
            }
        }
    __syncthreads();
    if (t < 64) { as2[n0 + t] = asr[t]; ad2[n0 + t] = adr[t]; }
}

// ======================= K5: GAT2 edge MFMA + partial pool =======
__global__ __launch_bounds__(512) void gat2_edge_mfma(
    const unsigned short* __restrict__ ht2, const float* __restrict__ as2,
    const float* __restrict__ ad2, const unsigned int* __restrict__ mcsr,
    const int* __restrict__ rowstart, const int* __restrict__ rowlen,
    float* __restrict__ pl8)
{
    int g = blockIdx.x, by = blockIdx.y;
    __shared__ unsigned short ht[64 * 256];    // 32 KB
    __shared__ unsigned short Mb[32 * 256];    // 16 KB
    __shared__ float asl[NNODE], adl[NNODE], u1[NNODE], u2[NNODE];
    __shared__ float v1[NNODE], v2[NNODE], den[32];
    __shared__ float wred[8];
    __shared__ float pool[64];
    int t = threadIdx.x;

    float va = -1e30f, vd = 0.f;
    if (t < NNODE) {
        va = as2[g * NNODE + t];
        vd = ad2[g * NNODE + t];
        asl[t] = va; adl[t] = vd;
    }
    if (t < 64) pool[t] = 0.f;
    {
        float mv = va;
        #pragma unroll
        for (int d = 32; d; d >>= 1) mv = fmaxf(mv, __shfl_xor(mv, d));
        if ((t & 63) == 0) wred[t >> 6] = mv;
    }
    __syncthreads();
    if (t < NNODE) {
        float M = fmaxf(fmaxf(wred[0], wred[1]), fmaxf(wred[2], wred[3]));
        float mt = lrelu02(M + vd);
        v1[t] = __expf(vd - mt);
        v2[t] = __expf(0.2f * vd - mt);
        u1[t] = __expf(va);
        u2[t] = __expf(0.2f * va);
    }
    for (int i = t; i < 2048; i += 512) {
        int c = i >> 5, sg = i & 31;
        bf16x8 v = *(const bf16x8*)&ht2[(size_t)(g * 64 + c) * 256 + sg * 8];
        *(bf16x8*)&ht[c * 256 + ((sg ^ (c & 31)) << 3)] = v;
    }
    float4 z4 = make_float4(0.f, 0.f, 0.f, 0.f);
    for (int i = t; i < 1024; i += 512) ((float4*)Mb)[i] = z4;
    __syncthreads();

    int w = t >> 6, l = t & 63;
    int lrow = l & 15, lk = l >> 4;
    int r0 = by * 32;

    for (int ri = w; ri < 32; ri += 8) {
        int d = r0 + ri;
        int rs = rowstart[g * NNODE + d], len = rowlen[g * NNODE + d];
        float adv = adl[d], vd1 = v1[d], vd2 = v2[d];
        float ss = 0.f;
        for (int e0 = 0; e0 < len; e0 += 64) {
            int e = e0 + l;
            float p = 0.f;
            if (e < len) {
                unsigned ent = mcsr[(size_t)g * E_PER + rs + e];
                int s = ent & 0xFFFFu;
                float c = (float)(ent >> 16);
                float z = asl[s] + adv;
                p = c * (z > 0.f ? u1[s] * vd1 : u2[s] * vd2);
                Mb[ri * 256 + ((((s >> 3) ^ (ri & 7)) << 3) | (s & 7))] = f2bf(p);
            }
            ss += p;
        }
        #pragma unroll
        for (int m = 1; m < 64; m <<= 1) ss += __shfl_xor(ss, m);
        if (l == 0) den[ri] = ss;
    }
    __syncthreads();

    int mt = w & 1, nt = w >> 1;
    f32x4 acc = {0.f, 0.f, 0.f, 0.f};
    int ar = mt * 16 + lrow;
    int c = nt * 16 + lrow;
    #pragma unroll
    for (int kb = 0; kb < 8; ++kb) {
        int oct = kb * 4 + lk;
        bf16x8 a = *(const bf16x8*)&Mb[ar * 256 + ((oct ^ (ar & 7)) << 3)];
        bf16x8 b = *(const bf16x8*)&ht[c * 256 + ((oct ^ (c & 31)) << 3)];
        acc = __builtin_amdgcn_mfma_f32_16x16x32_bf16(a, b, acc, 0, 0, 0);
    }
    float ps = 0.f;
    #pragma unroll
    for (int r = 0; r < 4; ++r) {
        int rl = mt * 16 + lk * 4 + r;
        ps = fmaf(acc[r], 1.f / (den[rl] + 1e-16f), ps);
    }
    ps += __shfl_xor(ps, 16);
    ps += __shfl_xor(ps, 32);
    if (l < 16) atomicAdd(&pool[nt * 16 + lrow], ps);
    __syncthreads();
    if (t < 64) pl8[(size_t)(g * 8 + by) * 64 + t] = pool[t];
}

// ======================= K6: pool-combine + classifier ===========
__global__ __launch_bounds__(64) void cls_kernel(
    const float* __restrict__ pl8, const float* __restrict__ bias2,
    const float* __restrict__ w1, const float* __restrict__ b1,
    const float* __restrict__ w2, const float* __restrict__ b2,
    float* __restrict__ outv, float* __restrict__ pooled)
{
    int g = blockIdx.x, c = threadIdx.x;
    float po = 0.f;
    #pragma unroll
    for (int q = 0; q < 8; ++q) po += pl8[(size_t)(g * 8 + q) * 64 + c];
    po = po * (1.f / 256.f) + bias2[c];
    pooled[g * 64 + c] = po;
    __shared__ float poL[64];
    poL[c] = po;
    __syncthreads();
    float acc = b1[c];
    for (int k = 0; k < 64; ++k) acc = fmaf(poL[k], w1[k * 64 + c], acc);
    acc = fmaxf(acc, 0.f);
    float contrib = acc * w2[c];
    #pragma unroll
    for (int d = 32; d; d >>= 1) contrib += __shfl_xor(contrib, d);
    if (c == 0) outv[g] = 1.f / (1.f + __expf(-contrib));
}

extern "C" void kernel_launch(void* const* d_in, const int* in_sizes, int n_in,
                              void* d_out, int out_size, void* d_ws, size_t ws_size,
                              hipStream_t stream) {
    const float* omics   = (const float*)d_in[0];
    const float* w_omics = (const float*)d_in[1];
    const float* b_omics = (const float*)d_in[2];
    const float* rot     = (const float*)d_in[3];
    const float* bn_g    = (const float*)d_in[4];
    const float* bn_b    = (const float*)d_in[5];
    const float* bn_m    = (const float*)d_in[6];
    const float* bn_v    = (const float*)d_in[7];
    const float* gat1_w  = (const float*)d_in[8];
    const float* att_s1  = (const float*)d_in[9];
    const float* att_d1  = (const float*)d_in[10];
    const float* bias1   = (const float*)d_in[11];
    const float* gat2_w  = (const float*)d_in[12];
    const float* att_s2  = (const float*)d_in[13];
    const float* att_d2  = (const float*)d_in[14];
    const float* bias2   = (const float*)d_in[15];
    const float* cls_w1  = (const float*)d_in[16];
    const float* cls_b1  = (const float*)d_in[17];
    const float* cls_w2  = (const float*)d_in[18];
    const float* cls_b2  = (const float*)d_in[19];
    const int*   eidx    = (const int*)d_in[20];

    float* ws = (float*)d_ws;
    size_t o_xb   = 0;                                        // bf16 NUM_NODES*64
    size_t o_ht1  = o_xb  + (size_t)NUM_NODES * 64 / 2;       // bf16 G*4*64*256
    size_t o_as1  = o_ht1 + (size_t)G * HEADS * 64 * 256 / 2;
    size_t o_ad1  = o_as1 + (size_t)NUM_NODES * HEADS;
    size_t o_x2b  = o_ad1 + (size_t)NUM_NODES * HEADS;        // bf16 NUM_NODES*256
    size_t o_ht2  = o_x2b + (size_t)NUM_NODES * 256 / 2;      // bf16 G*64*256
    size_t o_as2  = o_ht2 + (size_t)G * 64 * 256 / 2;
    size_t o_ad2  = o_as2 + (size_t)NUM_NODES;
    size_t o_pl8  = o_ad2 + (size_t)NUM_NODES;
    size_t o_mcsr = o_pl8 + (size_t)G * 8 * 64;
    size_t o_rs   = o_mcsr + (size_t)E_TOTAL;
    size_t o_rl   = o_rs + (size_t)NUM_NODES;
    size_t o_wt1  = o_rl + (size_t)NUM_NODES;                 // bf16 16384
    size_t o_wt2  = o_wt1 + 8192;

    unsigned short* xb  = (unsigned short*)(ws + o_xb);
    unsigned short* ht1 = (unsigned short*)(ws + o_ht1);
    float* as1 = ws + o_as1;
    float* ad1 = ws + o_ad1;
    unsigned short* x2b = (unsigned short*)(ws + o_x2b);
    unsigned short* ht2 = (unsigned short*)(ws + o_ht2);
    float* as2 = ws + o_as2;
    float* ad2 = ws + o_ad2;
    float* pl8 = ws + o_pl8;
    unsigned int* mcsr = (unsigned int*)(ws + o_mcsr);
    int* rowstart_ws = (int*)(ws + o_rs);
    int* rowlen_ws   = (int*)(ws + o_rl);
    unsigned short* wt1 = (unsigned short*)(ws + o_wt1);
    unsigned short* wt2 = (unsigned short*)(ws + o_wt2);

    float* outv   = (float*)d_out;        // [64]
    float* pooled = (float*)d_out + G;    // [64*64]

    prep_w<<<64, 256, 0, stream>>>(gat1_w, gat2_w, wt1, wt2);
    csr_build<<<dim3(G, CSR_SPLIT), 512, 0, stream>>>(eidx, mcsr, rowstart_ws, rowlen_ws);
    enc_kernel<<<256, 256, 0, stream>>>(omics, w_omics, b_omics, rot,
                                        bn_g, bn_b, bn_m, bn_v, xb);
    gat1_lin_mfma<<<256, 512, 0, stream>>>(xb, wt1, att_s1, att_d1, ht1, as1, ad1);
    gat1_edge_mfma<<<dim3(G, HEADS), 512, 0, stream>>>(
        ht1, as1, ad1, mcsr, rowstart_ws, rowlen_ws, bias1, x2b);
    gat2_lin_mfma<<<256, 512, 0, stream>>>(x2b, wt2, att_s2, att_d2, ht2, as2, ad2);
    gat2_edge_mfma<<<dim3(G, 8), 512, 0, stream>>>(
        ht2, as2, ad2, mcsr, rowstart_ws, rowlen_ws, pl8);
    cls_kernel<<<G, 64, 0, stream>>>(pl8, bias2, cls_w1, cls_b1, cls_w2, cls_b2,
                                     outv, pooled);
}

// Round 9
// 86.133 us; speedup vs baseline: 1.5891x; 1.1838x over previous
//
#include <hip/hip_runtime.h>
#include <hip/hip_bf16.h>
#include <math.h>

#define G 64
#define NNODE 256      // nodes per graph (= O)
#define D_IN 128
#define HDIM 64
#define HEADS 4
#define E_PER 8192
#define NUM_NODES (G * NNODE)
#define E_TOTAL (G * E_PER)
#define BN_EPS 1e-5f

#define CSR_SPLIT 8
#define CSR_ROWS (NNODE / CSR_SPLIT)
#define CSR_BUF 2176

typedef __attribute__((ext_vector_type(8))) short bf16x8;
typedef __attribute__((ext_vector_type(4))) float f32x4;

__device__ __forceinline__ float lrelu02(float x) { return x > 0.f ? x : 0.2f * x; }
__device__ __forceinline__ unsigned short f2bf(float f) {
    unsigned u = __float_as_uint(f);
    return (unsigned short)((u + 0x7FFFu + ((u >> 16) & 1u)) >> 16);
}
__device__ __forceinline__ unsigned long long pk4(float a, float b, float c, float d) {
    return (unsigned long long)f2bf(a)
         | ((unsigned long long)f2bf(b) << 16)
         | ((unsigned long long)f2bf(c) << 32)
         | ((unsigned long long)f2bf(d) << 48);
}

// ======================= K-1: weight transpose to bf16 ===========
__global__ __launch_bounds__(256) void prep_w(
    const float* __restrict__ w1, const float* __restrict__ w2,
    unsigned short* __restrict__ wt1, unsigned short* __restrict__ wt2)
{
    int t = blockIdx.x * 256 + threadIdx.x;      // 64 blocks -> 16384
    int c = t >> 6, k = t & 63;
    wt1[c * 64 + k] = f2bf(w1[k * 256 + c]);     // [c 256][k 64]
    int c2 = t >> 8, k2 = t & 255;
    wt2[c2 * 256 + k2] = f2bf(w2[k2 * 64 + c2]); // [c 64][k 256]
}

// ======================= K0: merged+sorted CSR build =============
__global__ __launch_bounds__(512) void csr_build(
    const int* __restrict__ eidx, unsigned int* __restrict__ mcsr,
    int* __restrict__ rowstart, int* __restrict__ rowlen)
{
    int g = blockIdx.x, by = blockIdx.y;
    __shared__ unsigned short ssrcL[CSR_BUF];
    __shared__ int cnt[NNODE], offv[NNODE + 1];
    __shared__ int cur[CSR_ROWS];
    __shared__ int wsum[8];
    int t = threadIdx.x;
    if (t < NNODE) cnt[t] = 0;
    __syncthreads();

    const int* srcp = eidx + (size_t)g * E_PER;
    const int* dstp = eidx + E_TOTAL + (size_t)g * E_PER;
    int base = g * NNODE;

    for (int e = t; e < E_PER; e += 512) atomicAdd(&cnt[dstp[e] - base], 1);
    __syncthreads();

    int vincl = (t < NNODE) ? cnt[t] : 0;
    #pragma unroll
    for (int d = 1; d < 64; d <<= 1) {
        int o = __shfl_up(vincl, d);
        if ((t & 63) >= d) vincl += o;
    }
    if (t < NNODE && (t & 63) == 63) wsum[t >> 6] = vincl;
    __syncthreads();
    if (t < NNODE) {
        int w = t >> 6;
        int add = 0;
        if (w > 0) add += wsum[0];
        if (w > 1) add += wsum[1];
        if (w > 2) add += wsum[2];
        offv[t] = vincl - cnt[t] + add;
    }
    if (t == 0) offv[NNODE] = E_PER;
    __syncthreads();

    int r0 = by * CSR_ROWS;
    int lb = offv[r0];
    if (t < CSR_ROWS) cur[t] = offv[r0 + t] - lb;
    __syncthreads();

    for (int e = t; e < E_PER; e += 512) {
        int d = dstp[e] - base - r0;
        if ((unsigned)d < CSR_ROWS) {
            int s = srcp[e] - base;
            int pos = atomicAdd(&cur[d], 1);
            ssrcL[pos] = (unsigned short)s;
        }
    }
    __syncthreads();

    int w = t >> 6, l = t & 63;
    for (int ri = w; ri < CSR_ROWS; ri += 8) {
        int r = r0 + ri;
        int rsg = offv[r], deg = offv[r + 1] - rsg;
        int ls = rsg - lb;
        if (deg <= 64) {
            unsigned v = (l < deg) ? (unsigned)ssrcL[ls + l] : 0xFFFFu;
            #pragma unroll
            for (int k = 2; k <= 64; k <<= 1) {
                #pragma unroll
                for (int j = k >> 1; j > 0; j >>= 1) {
                    unsigned pv = (unsigned)__shfl_xor((int)v, j);
                    bool up = ((l & k) == 0);
                    bool lower = ((l & j) == 0);
                    unsigned mn = v < pv ? v : pv;
                    unsigned mx = v < pv ? pv : v;
                    v = (up == lower) ? mn : mx;
                }
            }
            unsigned prev = (unsigned)__shfl_up((int)v, 1);
            bool lead = (l < deg) && (l == 0 || v != prev);
            unsigned long long L = __ballot(lead);
            if (lead) {
                unsigned long long gt = (l >= 63) ? 0ULL : (L & (~0ULL << (l + 1)));
                int nxt = gt ? __builtin_ctzll(gt) : deg;
                int count = nxt - l;
                unsigned long long below = (l == 0) ? 0ULL : (L & ((1ULL << l) - 1ULL));
                int rank = __builtin_popcountll(below);
                mcsr[(size_t)g * E_PER + rsg + rank] =
                    ((unsigned)count << 16) | (v & 0xFFFFu);
            }
            if (l == 0) {
                rowlen[g * NNODE + r] = __builtin_popcountll(L);
                rowstart[g * NNODE + r] = rsg;
            }
        } else if (l == 0) {
            for (int i = 1; i < deg; ++i) {
                unsigned short key = ssrcL[ls + i];
                int j = i - 1;
                while (j >= 0 && ssrcL[ls + j] > key) { ssrcL[ls + j + 1] = ssrcL[ls + j]; --j; }
                ssrcL[ls + j + 1] = key;
            }
            int m = 0, i = 0;
            while (i < deg) {
                int s0 = ssrcL[ls + i]; int c = 1;
                while (i + c < deg && ssrcL[ls + i + c] == s0) ++c;
                mcsr[(size_t)g * E_PER + rsg + m] = ((unsigned)c << 16) | (unsigned)s0;
                ++m; i += c;
            }
            rowlen[g * NNODE + r] = m;
            rowstart[g * NNODE + r] = rsg;
        }
    }
}

// ======================= K1: omics encoder (512 thr, bf16 out) ===
__global__ __launch_bounds__(512) void enc_kernel(
    const float* __restrict__ omics, const float* __restrict__ w,
    const float* __restrict__ b, const float* __restrict__ rot,
    const float* __restrict__ gamma, const float* __restrict__ beta,
    const float* __restrict__ mean, const float* __restrict__ var,
    unsigned short* __restrict__ xb)
{
    int o = blockIdx.x;
    __shared__ float Wl[D_IN * HDIM];
    __shared__ float Om[G * 132];
    int t = threadIdx.x;
    for (int i = t; i < D_IN * HDIM / 4; i += 512)
        ((float4*)Wl)[i] = ((const float4*)(w + (size_t)o * D_IN * HDIM))[i];
    for (int i = t; i < G * (D_IN / 4); i += 512) {
        int g = i >> 5, dq = i & 31;
        *((float4*)(Om + g * 132) + dq) =
            ((const float4*)(omics + ((size_t)g * NNODE + o) * D_IN))[dq];
    }
    __syncthreads();

    int cq = t & 15, gs = t >> 4;            // g = gi*32 + gs
    float4 acc[2];
    acc[0] = make_float4(0.f, 0.f, 0.f, 0.f);
    acc[1] = make_float4(0.f, 0.f, 0.f, 0.f);

    for (int d = 0; d < D_IN; ++d) {
        float4 wv = *(const float4*)&Wl[d * 64 + cq * 4];
        #pragma unroll
        for (int gi = 0; gi < 2; ++gi) {
            float ov = Om[(gi * 32 + gs) * 132 + d];
            acc[gi].x = fmaf(ov, wv.x, acc[gi].x);
            acc[gi].y = fmaf(ov, wv.y, acc[gi].y);
            acc[gi].z = fmaf(ov, wv.z, acc[gi].z);
            acc[gi].w = fmaf(ov, wv.w, acc[gi].w);
        }
    }

    float4 bv = ((const float4*)b)[o * 16 + cq];
    float4 rv = ((const float4*)rot)[o * 16 + cq];
    float4 mv = ((const float4*)mean)[o * 16 + cq];
    float4 vv = ((const float4*)var)[o * 16 + cq];
    float4 gv = ((const float4*)gamma)[o * 16 + cq];
    float4 be = ((const float4*)beta)[o * 16 + cq];
    float4 sc, kk;
    sc.x = cosf(rv.x) + sinf(rv.x); sc.y = cosf(rv.y) + sinf(rv.y);
    sc.z = cosf(rv.z) + sinf(rv.z); sc.w = cosf(rv.w) + sinf(rv.w);
    kk.x = gv.x * rsqrtf(vv.x + BN_EPS); kk.y = gv.y * rsqrtf(vv.y + BN_EPS);
    kk.z = gv.z * rsqrtf(vv.z + BN_EPS); kk.w = gv.w * rsqrtf(vv.w + BN_EPS);

    #pragma unroll
    for (int gi = 0; gi < 2; ++gi) {
        int g = gi * 32 + gs;
        float4 v;
        v.x = fmaxf((acc[gi].x + bv.x) * sc.x, 0.f);
        v.y = fmaxf((acc[gi].y + bv.y) * sc.y, 0.f);
        v.z = fmaxf((acc[gi].z + bv.z) * sc.z, 0.f);
        v.w = fmaxf((acc[gi].w + bv.w) * sc.w, 0.f);
        v.x = (v.x - mv.x) * kk.x + be.x;
        v.y = (v.y - mv.y) * kk.y + be.y;
        v.z = (v.z - mv.z) * kk.z + be.z;
        v.w = (v.w - mv.w) * kk.w + be.w;
        *(unsigned long long*)&xb[((size_t)(g * NNODE + o)) * 64 + cq * 4] =
            pk4(v.x, v.y, v.z, v.w);
    }
}

// ======================= K2: GAT1 linear via MFMA ================
__global__ __launch_bounds__(512) void gat1_lin_mfma(
    const unsigned short* __restrict__ xb, const unsigned short* __restrict__ wt1,
    const float* __restrict__ att_s, const float* __restrict__ att_d,
    unsigned short* __restrict__ ht1, float* __restrict__ as1, float* __restrict__ ad1)
{
    int blk = blockIdx.x;
    int n0 = blk * 64;
    int g = n0 >> 8, soff = n0 & 255;
    __shared__ unsigned short Ab[64 * 64];
    __shared__ unsigned short Bb[256 * 64];
    int t = threadIdx.x;
    {
        int node = t >> 3, kg = t & 7;
        bf16x8 v = *(const bf16x8*)&xb[(size_t)(n0 + node) * 64 + kg * 8];
        *(bf16x8*)&Ab[node * 64 + ((kg ^ (node & 7)) << 3)] = v;
    }
    for (int i = t; i < 2048; i += 512) {
        int c = i >> 3, kg = i & 7;
        bf16x8 v = *(const bf16x8*)&wt1[c * 64 + kg * 8];
        *(bf16x8*)&Bb[c * 64 + ((kg ^ (c & 7)) << 3)] = v;
    }
    __syncthreads();

    int w = t >> 6, l = t & 63;
    int lrow = l & 15, lk = l >> 4;
    int mt = w >> 1, hh0 = (w & 1) * 2;
    int arow = mt * 16 + lrow;
    float asp[2][4], adp[2][4];
    #pragma unroll
    for (int hi = 0; hi < 2; ++hi)
        #pragma unroll
        for (int r = 0; r < 4; ++r) { asp[hi][r] = 0.f; adp[hi][r] = 0.f; }

    for (int ntl = 0; ntl < 8; ++ntl) {
        int nt = (w & 1) * 8 + ntl;
        int c = nt * 16 + lrow;
        f32x4 acc = {0.f, 0.f, 0.f, 0.f};
        #pragma unroll
        for (int kb = 0; kb < 2; ++kb) {
            int kg = kb * 4 + lk;
            bf16x8 a = *(const bf16x8*)&Ab[arow * 64 + ((kg ^ (arow & 7)) << 3)];
            bf16x8 b = *(const bf16x8*)&Bb[c * 64 + ((kg ^ (c & 7)) << 3)];
            acc = __builtin_amdgcn_mfma_f32_16x16x32_bf16(a, b, acc, 0, 0, 0);
        }
        int head = c >> 6, ch = c & 63;
        int sb = soff + mt * 16 + lk * 4;
        *(unsigned long long*)&ht1[(size_t)((g * HEADS + head) * 64 + ch) * 256 + sb] =
            pk4(acc[0], acc[1], acc[2], acc[3]);
        float av = att_s[c], dv = att_d[c];
        int hi = ntl >> 2;
        #pragma unroll
        for (int r = 0; r < 4; ++r) {
            asp[hi][r] = fmaf(acc[r], av, asp[hi][r]);
            adp[hi][r] = fmaf(acc[r], dv, adp[hi][r]);
        }
    }
    #pragma unroll
    for (int hi = 0; hi < 2; ++hi)
        #pragma unroll
        for (int r = 0; r < 4; ++r) {
            float a = asp[hi][r], d = adp[hi][r];
            a += __shfl_xor(a, 1); a += __shfl_xor(a, 2);
            a += __shfl_xor(a, 4); a += __shfl_xor(a, 8);
            d += __shfl_xor(d, 1); d += __shfl_xor(d, 2);
            d += __shfl_xor(d, 4); d += __shfl_xor(d, 8);
            if (lrow == 0) {
                int node = n0 + mt * 16 + lk * 4 + r;
                as1[node * HEADS + hh0 + hi] = a;
                ad1[node * HEADS + hh0 + hi] = d;
            }
        }
}

// ======================= K3: GAT1 edge via merged-CSR MFMA =======
// grid (G, HEADS, 2), 512 thr, ~70 KB LDS -> 2 blocks/CU.
// xs transpose staging aliased onto Mb (dead between MFMA and next zero).
__global__ __launch_bounds__(512) void gat1_edge_mfma(
    const unsigned short* __restrict__ ht1, const float* __restrict__ as1,
    const float* __restrict__ ad1, const unsigned int* __restrict__ mcsr,
    const int* __restrict__ rowstart, const int* __restrict__ rowlen,
    const float* __restrict__ bias1, unsigned short* __restrict__ x2b)
{
    int g = blockIdx.x, head = blockIdx.y, by = blockIdx.z;
    __shared__ unsigned short ht[64 * 256];    // 32 KB
    __shared__ unsigned short Mb[64 * 256];    // 32 KB (aliased as xs in epilogue)
    __shared__ float asl[NNODE], adl[NNODE], u1[NNODE], u2[NNODE];
    __shared__ float v1[NNODE], v2[NNODE], den[64];
    __shared__ float wred[8];
    unsigned short* xs = Mb;                   // 8 KB alias
    int t = threadIdx.x;

    float va = -1e30f, vd = 0.f;
    if (t < NNODE) {
        va = as1[(g * NNODE + t) * HEADS + head];
        vd = ad1[(g * NNODE + t) * HEADS + head];
        asl[t] = va; adl[t] = vd;
    }
    {
        float mv = va;
        #pragma unroll
        for (int d = 32; d; d >>= 1) mv = fmaxf(mv, __shfl_xor(mv, d));
        if ((t & 63) == 0) wred[t >> 6] = mv;
    }
    __syncthreads();
    if (t < NNODE) {
        float M = fmaxf(fmaxf(wred[0], wred[1]), fmaxf(wred[2], wred[3]));
        float mt = lrelu02(M + vd);
        v1[t] = __expf(vd - mt);
        v2[t] = __expf(0.2f * vd - mt);
        u1[t] = __expf(va);
        u2[t] = __expf(0.2f * va);
    }
    for (int i = t; i < 2048; i += 512) {
        int c = i >> 5, sg = i & 31;
        bf16x8 v = *(const bf16x8*)&ht1[(size_t)((g * HEADS + head) * 64 + c) * 256 + sg * 8];
        *(bf16x8*)&ht[c * 256 + ((sg ^ (c & 31)) << 3)] = v;
    }
    __syncthreads();

    int w = t >> 6, l = t & 63;
    int lrow = l & 15, lk = l >> 4;
    int mt = w & 3, nb = (w >> 2) * 2;
    int ar = mt * 16 + lrow;
    int c0 = nb * 16 + lrow, c1 = c0 + 16;
    float b0v = bias1[head * 64 + c0], b1v = bias1[head * 64 + c1];

    for (int qi = 0; qi < 2; ++qi) {
        int q = by * 2 + qi;
        int r0 = q * 64;
        float4 z4 = make_float4(0.f, 0.f, 0.f, 0.f);
        for (int i = t; i < 2048; i += 512) ((float4*)Mb)[i] = z4;
        __syncthreads();
        for (int ri = w; ri < 64; ri += 8) {
            int d = r0 + ri;
            int rs = rowstart[g * NNODE + d], len = rowlen[g * NNODE + d];
            float adv = adl[d], vd1 = v1[d], vd2 = v2[d];
            float ss = 0.f;
            for (int e0 = 0; e0 < len; e0 += 64) {
                int e = e0 + l;
                float p = 0.f;
                if (e < len) {
                    unsigned ent = mcsr[(size_t)g * E_PER + rs + e];
                    int s = ent & 0xFFFFu;
                    float c = (float)(ent >> 16);
                    float z = asl[s] + adv;
                    p = c * (z > 0.f ? u1[s] * vd1 : u2[s] * vd2);
                    Mb[ri * 256 + ((((s >> 3) ^ (ri & 7)) << 3) | (s & 7))] = f2bf(p);
                }
                ss += p;
            }
            #pragma unroll
            for (int m = 1; m < 64; m <<= 1) ss += __shfl_xor(ss, m);
            if (l == 0) den[ri] = ss;
        }
        __syncthreads();
        f32x4 acc0 = {0.f, 0.f, 0.f, 0.f};
        f32x4 acc1 = {0.f, 0.f, 0.f, 0.f};
        #pragma unroll
        for (int kb = 0; kb < 8; ++kb) {
            int oct = kb * 4 + lk;
            bf16x8 a = *(const bf16x8*)&Mb[ar * 256 + ((oct ^ (ar & 7)) << 3)];
            bf16x8 b0 = *(const bf16x8*)&ht[c0 * 256 + ((oct ^ (c0 & 31)) << 3)];
            bf16x8 b1 = *(const bf16x8*)&ht[c1 * 256 + ((oct ^ (c1 & 31)) << 3)];
            acc0 = __builtin_amdgcn_mfma_f32_16x16x32_bf16(a, b0, acc0, 0, 0, 0);
            acc1 = __builtin_amdgcn_mfma_f32_16x16x32_bf16(a, b1, acc1, 0, 0, 0);
        }
        __syncthreads();   // alias safety: all Mb reads done before xs writes
        #pragma unroll
        for (int r = 0; r < 4; ++r) {
            int rl = mt * 16 + lk * 4 + r;
            float inv = 1.f / (den[rl] + 1e-16f);
            float o0 = acc0[r] * inv + b0v;
            float o1 = acc1[r] * inv + b1v;
            o0 = o0 > 0.f ? o0 : expm1f(o0);
            o1 = o1 > 0.f ? o1 : expm1f(o1);
            xs[rl * 64 + c0] = f2bf(o0);
            xs[rl * 64 + c1] = f2bf(o1);
        }
        __syncthreads();
        {
            int row = t >> 3, cg = t & 7;
            bf16x8 v = *(const bf16x8*)&xs[row * 64 + cg * 8];
            *(bf16x8*)&x2b[(size_t)(g * NNODE + r0 + row) * 256 + head * 64 + cg * 8] = v;
        }
        __syncthreads();
    }
}

// ======================= K4: GAT2 linear via MFMA ================
__global__ __launch_bounds__(512) void gat2_lin_mfma(
    const unsigned short* __restrict__ x2b, const unsigned short* __restrict__ wt2,
    const float* __restrict__ att_s, const float* __restrict__ att_d,
    unsigned short* __restrict__ ht2, float* __restrict__ as2, float* __restrict__ ad2)
{
    int blk = blockIdx.x;
    int n0 = blk * 64;
    int g = n0 >> 8, soff = n0 & 255;
    __shared__ unsigned short Ab[64 * 256];
    __shared__ unsigned short Bb[64 * 256];
    __shared__ float asr[64], adr[64];
    int t = threadIdx.x;
    for (int i = t; i < 2048; i += 512) {
        int node = i >> 5, kg = i & 31;
        bf16x8 v = *(const bf16x8*)&x2b[(size_t)(n0 + node) * 256 + kg * 8];
        *(bf16x8*)&Ab[node * 256 + ((kg ^ (node & 31)) << 3)] = v;
    }
    for (int i = t; i < 2048; i += 512) {
        int c = i >> 5, kg = i & 31;
        bf16x8 v = *(const bf16x8*)&wt2[c * 256 + kg * 8];
        *(bf16x8*)&Bb[c * 256 + ((kg ^ (c & 31)) << 3)] = v;
    }
    if (t < 64) { asr[t] = 0.f; adr[t] = 0.f; }
    __syncthreads();

    int w = t >> 6, l = t & 63;
    int lrow = l & 15, lk = l >> 4;
    int mt = w & 3, nb = (w >> 2) * 2;
    int ar = mt * 16 + lrow;
    float asp[2][4], adp[2][4];
    #pragma unroll
    for (int ni = 0; ni < 2; ++ni)
        #pragma unroll
        for (int r = 0; r < 4; ++r) { asp[ni][r] = 0.f; adp[ni][r] = 0.f; }

    #pragma unroll
    for (int ni = 0; ni < 2; ++ni) {
        int c = (nb + ni) * 16 + lrow;
        f32x4 acc = {0.f, 0.f, 0.f, 0.f};
        #pragma unroll
        for (int ks = 0; ks < 8; ++ks) {
            int kg = ks * 4 + lk;
            bf16x8 a = *(const bf16x8*)&Ab[ar * 256 + ((kg ^ (ar & 31)) << 3)];
            bf16x8 b = *(const bf16x8*)&Bb[c * 256 + ((kg ^ (c & 31)) << 3)];
            acc = __builtin_amdgcn_mfma_f32_16x16x32_bf16(a, b, acc, 0, 0, 0);
        }
        int sb = soff + mt * 16 + lk * 4;
        *(unsigned long long*)&ht2[(size_t)(g * 64 + c) * 256 + sb] =
            pk4(acc[0], acc[1], acc[2], acc[3]);
        float av = att_s[c], dv = att_d[c];
        #pragma unroll
        for (int r = 0; r < 4; ++r) {
            asp[ni][r] = fmaf(acc[r], av, asp[ni][r]);
            adp[ni][r] = fmaf(acc[r], dv, adp[ni][r]);
        }
    }
    #pragma unroll
    for (int ni = 0; ni < 2; ++ni)
        #pragma unroll
        for (int r = 0; r < 4; ++r) {
            float a = asp[ni][r], d = adp[ni][r];
            a += __shfl_xor(a, 1); a += __shfl_xor(a, 2);
            a += __shfl_xor(a, 4); a += __shfl_xor(a, 8);
            d += __shfl_xor(d, 1); d += __shfl_xor(d, 2);
            d += __shfl_xor(d, 4); d += __shfl_xor(d, 8);
            if (lrow == 0) {
                int rl = mt * 16 + lk * 4 + r;
                atomicAdd(&asr[rl], a);
                atomicAdd(&adr[rl], d);
            }
        }
    __syncthreads();
    if (t < 64) { as2[n0 + t] = asr[t]; ad2[n0 + t] = adr[t]; }
}

// ======================= K5: GAT2 edge MFMA + partial pool =======
__global__ __launch_bounds__(512) void gat2_edge_mfma(
    const unsigned short* __restrict__ ht2, const float* __restrict__ as2,
    const float* __restrict__ ad2, const unsigned int* __restrict__ mcsr,
    const int* __restrict__ rowstart, const int* __restrict__ rowlen,
    float* __restrict__ pl8)
{
    int g = blockIdx.x, by = blockIdx.y;
    __shared__ unsigned short ht[64 * 256];
    __shared__ unsigned short Mb[32 * 256];
    __shared__ float asl[NNODE], adl[NNODE], u1[NNODE], u2[NNODE];
    __shared__ float v1[NNODE], v2[NNODE], den[32];
    __shared__ float wred[8];
    __shared__ float pool[64];
    int t = threadIdx.x;

    float va = -1e30f, vd = 0.f;
    if (t < NNODE) {
        va = as2[g * NNODE + t];
        vd = ad2[g * NNODE + t];
        asl[t] = va; adl[t] = vd;
    }
    if (t < 64) pool[t] = 0.f;
    {
        float mv = va;
        #pragma unroll
        for (int d = 32; d; d >>= 1) mv = fmaxf(mv, __shfl_xor(mv, d));
        if ((t & 63) == 0) wred[t >> 6] = mv;
    }
    __syncthreads();
    if (t < NNODE) {
        float M = fmaxf(fmaxf(wred[0], wred[1]), fmaxf(wred[2], wred[3]));
        float mt = lrelu02(M + vd);
        v1[t] = __expf(vd - mt);
        v2[t] = __expf(0.2f * vd - mt);
        u1[t] = __expf(va);
        u2[t] = __expf(0.2f * va);
    }
    for (int i = t; i < 2048; i += 512) {
        int c = i >> 5, sg = i & 31;
        bf16x8 v = *(const bf16x8*)&ht2[(size_t)(g * 64 + c) * 256 + sg * 8];
        *(bf16x8*)&ht[c * 256 + ((sg ^ (c & 31)) << 3)] = v;
    }
    float4 z4 = make_float4(0.f, 0.f, 0.f, 0.f);
    for (int i = t; i < 1024; i += 512) ((float4*)Mb)[i] = z4;
    __syncthreads();

    int w = t >> 6, l = t & 63;
    int lrow = l & 15, lk = l >> 4;
    int r0 = by * 32;

    for (int ri = w; ri < 32; ri += 8) {
        int d = r0 + ri;
        int rs = rowstart[g * NNODE + d], len = rowlen[g * NNODE + d];
        float adv = adl[d], vd1 = v1[d], vd2 = v2[d];
        float ss = 0.f;
        for (int e0 = 0; e0 < len; e0 += 64) {
            int e = e0 + l;
            float p = 0.f;
            if (e < len) {
                unsigned ent = mcsr[(size_t)g * E_PER + rs + e];
                int s = ent & 0xFFFFu;
                float c = (float)(ent >> 16);
                float z = asl[s] + adv;
                p = c * (z > 0.f ? u1[s] * vd1 : u2[s] * vd2);
                Mb[ri * 256 + ((((s >> 3) ^ (ri & 7)) << 3) | (s & 7))] = f2bf(p);
            }
            ss += p;
        }
        #pragma unroll
        for (int m = 1; m < 64; m <<= 1) ss += __shfl_xor(ss, m);
        if (l == 0) den[ri] = ss;
    }
    __syncthreads();

    int mt = w & 1, nt = w >> 1;
    f32x4 acc = {0.f, 0.f, 0.f, 0.f};
    int ar = mt * 16 + lrow;
    int c = nt * 16 + lrow;
    #pragma unroll
    for (int kb = 0; kb < 8; ++kb) {
        int oct = kb * 4 + lk;
        bf16x8 a = *(const bf16x8*)&Mb[ar * 256 + ((oct ^ (ar & 7)) << 3)];
        bf16x8 b = *(const bf16x8*)&ht[c * 256 + ((oct ^ (c & 31)) << 3)];
        acc = __builtin_amdgcn_mfma_f32_16x16x32_bf16(a, b, acc, 0, 0, 0);
    }
    float ps = 0.f;
    #pragma unroll
    for (int r = 0; r < 4; ++r) {
        int rl = mt * 16 + lk * 4 + r;
        ps = fmaf(acc[r], 1.f / (den[rl] + 1e-16f), ps);
    }
    ps += __shfl_xor(ps, 16);
    ps += __shfl_xor(ps, 32);
    if (l < 16) atomicAdd(&pool[nt * 16 + lrow], ps);
    __syncthreads();
    if (t < 64) pl8[(size_t)(g * 8 + by) * 64 + t] = pool[t];
}

// ======================= K6: pool-combine + classifier ===========
__global__ __launch_bounds__(64) void cls_kernel(
    const float* __restrict__ pl8, const float* __restrict__ bias2,
    const float* __restrict__ w1, const float* __restrict__ b1,
    const float* __restrict__ w2, const float* __restrict__ b2,
    float* __restrict__ outv, float* __restrict__ pooled)
{
    int g = blockIdx.x, c = threadIdx.x;
    float po = 0.f;
    #pragma unroll
    for (int q = 0; q < 8; ++q) po += pl8[(size_t)(g * 8 + q) * 64 + c];
    po = po * (1.f / 256.f) + bias2[c];
    pooled[g * 64 + c] = po;
    __shared__ float poL[64];
    poL[c] = po;
    __syncthreads();
    float acc = b1[c];
    for (int k = 0; k < 64; ++k) acc = fmaf(poL[k], w1[k * 64 + c], acc);
    acc = fmaxf(acc, 0.f);
    float contrib = acc * w2[c];
    #pragma unroll
    for (int d = 32; d; d >>= 1) contrib += __shfl_xor(contrib, d);
    if (c == 0) outv[g] = 1.f / (1.f + __expf(-contrib));
}

extern "C" void kernel_launch(void* const* d_in, const int* in_sizes, int n_in,
                              void* d_out, int out_size, void* d_ws, size_t ws_size,
                              hipStream_t stream) {
    const float* omics   = (const float*)d_in[0];
    const float* w_omics = (const float*)d_in[1];
    const float* b_omics = (const float*)d_in[2];
    const float* rot     = (const float*)d_in[3];
    const float* bn_g    = (const float*)d_in[4];
    const float* bn_b    = (const float*)d_in[5];
    const float* bn_m    = (const float*)d_in[6];
    const float* bn_v    = (const float*)d_in[7];
    const float* gat1_w  = (const float*)d_in[8];
    const float* att_s1  = (const float*)d_in[9];
    const float* att_d1  = (const float*)d_in[10];
    const float* bias1   = (const float*)d_in[11];
    const float* gat2_w  = (const float*)d_in[12];
    const float* att_s2  = (const float*)d_in[13];
    const float* att_d2  = (const float*)d_in[14];
    const float* bias2   = (const float*)d_in[15];
    const float* cls_w1  = (const float*)d_in[16];
    const float* cls_b1  = (const float*)d_in[17];
    const float* cls_w2  = (const float*)d_in[18];
    const float* cls_b2  = (const float*)d_in[19];
    const int*   eidx    = (const int*)d_in[20];

    float* ws = (float*)d_ws;
    size_t o_xb   = 0;
    size_t o_ht1  = o_xb  + (size_t)NUM_NODES * 64 / 2;
    size_t o_as1  = o_ht1 + (size_t)G * HEADS * 64 * 256 / 2;
    size_t o_ad1  = o_as1 + (size_t)NUM_NODES * HEADS;
    size_t o_x2b  = o_ad1 + (size_t)NUM_NODES * HEADS;
    size_t o_ht2  = o_x2b + (size_t)NUM_NODES * 256 / 2;
    size_t o_as2  = o_ht2 + (size_t)G * 64 * 256 / 2;
    size_t o_ad2  = o_as2 + (size_t)NUM_NODES;
    size_t o_pl8  = o_ad2 + (size_t)NUM_NODES;
    size_t o_mcsr = o_pl8 + (size_t)G * 8 * 64;
    size_t o_rs   = o_mcsr + (size_t)E_TOTAL;
    size_t o_rl   = o_rs + (size_t)NUM_NODES;
    size_t o_wt1  = o_rl + (size_t)NUM_NODES;
    size_t o_wt2  = o_wt1 + 8192;

    unsigned short* xb  = (unsigned short*)(ws + o_xb);
    unsigned short* ht1 = (unsigned short*)(ws + o_ht1);
    float* as1 = ws + o_as1;
    float* ad1 = ws + o_ad1;
    unsigned short* x2b = (unsigned short*)(ws + o_x2b);
    unsigned short* ht2 = (unsigned short*)(ws + o_ht2);
    float* as2 = ws + o_as2;
    float* ad2 = ws + o_ad2;
    float* pl8 = ws + o_pl8;
    unsigned int* mcsr = (unsigned int*)(ws + o_mcsr);
    int* rowstart_ws = (int*)(ws + o_rs);
    int* rowlen_ws   = (int*)(ws + o_rl);
    unsigned short* wt1 = (unsigned short*)(ws + o_wt1);
    unsigned short* wt2 = (unsigned short*)(ws + o_wt2);

    float* outv   = (float*)d_out;        // [64]
    float* pooled = (float*)d_out + G;    // [64*64]

    prep_w<<<64, 256, 0, stream>>>(gat1_w, gat2_w, wt1, wt2);
    csr_build<<<dim3(G, CSR_SPLIT), 512, 0, stream>>>(eidx, mcsr, rowstart_ws, rowlen_ws);
    enc_kernel<<<256, 512, 0, stream>>>(omics, w_omics, b_omics, rot,
                                        bn_g, bn_b, bn_m, bn_v, xb);
    gat1_lin_mfma<<<256, 512, 0, stream>>>(xb, wt1, att_s1, att_d1, ht1, as1, ad1);
    gat1_edge_mfma<<<dim3(G, HEADS, 2), 512, 0, stream>>>(
        ht1, as1, ad1, mcsr, rowstart_ws, rowlen_ws, bias1, x2b);
    gat2_lin_mfma<<<256, 512, 0, stream>>>(x2b, wt2, att_s2, att_d2, ht2, as2, ad2);
    gat2_edge_mfma<<<dim3(G, 8), 512, 0, stream>>>(
        ht2, as2, ad2, mcsr, rowstart_ws, rowlen_ws, pl8);
    cls_kernel<<<G, 64, 0, stream>>>(pl8, bias2, cls_w1, cls_b1, cls_w2, cls_b2,
                                     outv, pooled);
}